// Round 8
// baseline (410.269 us; speedup 1.0000x reference)
//
#include <hip/hip_runtime.h>

#define BH  24
#define SEQ 4096
#define DIM 128
#define FF  256
#define CHK 128
#define NC  32
#define SLOT (FF*DIM)

typedef unsigned short u16;
typedef unsigned int   u32;
typedef short  s16x8 __attribute__((ext_vector_type(8)));
typedef float  f32x4 __attribute__((ext_vector_type(4)));

#define MFMA16(a,b,c) __builtin_amdgcn_mfma_f32_16x16x32_bf16(a,b,c,0,0,0)

static __device__ __forceinline__ float bf2f(u16 u) {
    return __uint_as_float(((u32)u) << 16);
}
static __device__ __forceinline__ u16 f2bf(float f) {
    u32 u = __float_as_uint(f);
    u += 0x7fffu + ((u >> 16) & 1u);
    return (u16)(u >> 16);
}
// packed RNE f32x2 -> bf16x2 (lo in [15:0], hi in [31:16])
static __device__ __forceinline__ u32 cvtpk(float lo, float hi) {
    u32 r;
    asm("v_cvt_pk_bf16_f32 %0, %1, %2" : "=v"(r) : "v"(lo), "v"(hi));
    return r;
}

// ---------------- weight prep: transposed, padded, bf16 ----------------------
__global__ __launch_bounds__(256) void prep_kernel(
    const float* __restrict__ w1, const float* __restrict__ w2,
    u16* __restrict__ w1t, u16* __restrict__ w2t)
{
    int idx = blockIdx.x * 256 + threadIdx.x;
    int stride = gridDim.x * 256;
    for (int i = idx; i < 256*136; i += stride) {
        int f = i / 136, d = i - f*136;
        w1t[i] = (d < 128) ? f2bf(w1[d*FF + f]) : (u16)0;
    }
    for (int i = idx; i < 256*264; i += stride) {
        int e = i / 264, f = i - e*264;
        w2t[i] = (f < 256) ? f2bf(w2[f*FF + e]) : (u16)0;
    }
}

// ---------------- fused phi via MFMA: y = silu(x@W1+b1)@W2 + b2 --------------
// 512 threads / 8 waves: wf = w&3 (f/e group of 64), wt = w>>2 (token grp 32).
// FLIPPED orientation: C[f][token] / C[e][token] -> lane's 4 regs are
// CONTIGUOUS in f/e -> cvt_pk packing, 8B HS writes, direct Y global stores.
#define PTOK 64
#define XS_OFF   0
#define HS_OFF   0
#define ARENA_U16 16896   // 33,792 B  (HS 64x264; XS 64x136 overlaps)

__global__ __launch_bounds__(512) void phi_fused_kernel(
    const float* __restrict__ xq, const float* __restrict__ xk,
    const float* __restrict__ b1, const float* __restrict__ b2,
    const u16* __restrict__ w1t, const u16* __restrict__ w2t,
    u16* __restrict__ yq, u16* __restrict__ yk)
{
    __shared__ __align__(16) u16 arena[ARENA_U16];
    const int tid = threadIdx.x;
    int b = blockIdx.x;
    const int nB = (BH*SEQ)/PTOK;   // 1536
    const float* xin; u16* yout;
    if (b < nB) { xin = xq; yout = yq; }
    else        { xin = xk; yout = yk; b -= nB; }
    const size_t tok0 = (size_t)b * PTOK;

    const int w = tid >> 6, lane = tid & 63;
    const int m = lane & 15, q = lane >> 4;
    const int wf = w & 3, wt = w >> 2;
    const f32x4 zero4 = {0.f, 0.f, 0.f, 0.f};

    // ---- stage XS (fp32 -> bf16 via cvt_pk), [64][136] ---------------------
    {
        const float4* xsrc = reinterpret_cast<const float4*>(xin + tok0*DIM);
        for (int i = tid; i < PTOK*DIM/4; i += 512) {
            int row = i >> 5, c4 = i & 31;
            float4 xv = xsrc[i];
            *reinterpret_cast<uint2*>(arena + XS_OFF + row*136 + c4*4) =
                make_uint2(cvtpk(xv.x, xv.y), cvtpk(xv.z, xv.w));
        }
    }
    __syncthreads();   // sync1: XS visible

    // ---- GEMM1: C[f][token] = W1^T x X ; A = w1t rows(f), B = XS rows(tok) -
    f32x4 acc[4][2];
    #pragma unroll
    for (int fi = 0; fi < 4; ++fi)
        #pragma unroll
        for (int tj = 0; tj < 2; ++tj) acc[fi][tj] = zero4;

    #pragma unroll
    for (int kk = 0; kk < 4; ++kk) {
        const int ko = kk*32 + q*8;
        s16x8 a[4], bb[2];
        #pragma unroll
        for (int fi = 0; fi < 4; ++fi)
            a[fi] = *reinterpret_cast<const s16x8*>(w1t + (size_t)(wf*64 + fi*16 + m)*136 + ko);
        #pragma unroll
        for (int tj = 0; tj < 2; ++tj)
            bb[tj] = *reinterpret_cast<const s16x8*>(arena + XS_OFF + (wt*32 + tj*16 + m)*136 + ko);
        #pragma unroll
        for (int fi = 0; fi < 4; ++fi)
            #pragma unroll
            for (int tj = 0; tj < 2; ++tj)
                acc[fi][tj] = MFMA16(a[fi], bb[tj], acc[fi][tj]);
    }
    __syncthreads();   // sync2: XS reads done; HS overwrites that space

    // ---- bias + SiLU -> HS [token][f] stride 264, 8B packed writes ---------
    #pragma unroll
    for (int fi = 0; fi < 4; ++fi) {
        const int f0 = wf*64 + fi*16 + q*4;
        const float4 b1v = *reinterpret_cast<const float4*>(b1 + f0);
        #pragma unroll
        for (int tj = 0; tj < 2; ++tj) {
            const int token = wt*32 + tj*16 + m;
            float h[4];
            h[0] = acc[fi][tj][0] + b1v.x;
            h[1] = acc[fi][tj][1] + b1v.y;
            h[2] = acc[fi][tj][2] + b1v.z;
            h[3] = acc[fi][tj][3] + b1v.w;
            #pragma unroll
            for (int r = 0; r < 4; ++r) h[r] = h[r] / (1.0f + __expf(-h[r]));
            *reinterpret_cast<uint2*>(arena + HS_OFF + (size_t)token*264 + f0) =
                make_uint2(cvtpk(h[0], h[1]), cvtpk(h[2], h[3]));
        }
    }
    __syncthreads();   // sync3: HS visible

    // ---- GEMM2: C[e][token] = W2^T x H ; A = w2t rows(e), B = HS rows(tok) -
    f32x4 acc2[4][2];
    #pragma unroll
    for (int ei = 0; ei < 4; ++ei)
        #pragma unroll
        for (int tj = 0; tj < 2; ++tj) acc2[ei][tj] = zero4;

    #pragma unroll
    for (int kk = 0; kk < 8; ++kk) {
        const int ko = kk*32 + q*8;
        s16x8 a[4], bb[2];
        #pragma unroll
        for (int ei = 0; ei < 4; ++ei)
            a[ei] = *reinterpret_cast<const s16x8*>(w2t + (size_t)(wf*64 + ei*16 + m)*264 + ko);
        #pragma unroll
        for (int tj = 0; tj < 2; ++tj)
            bb[tj] = *reinterpret_cast<const s16x8*>(arena + HS_OFF + (size_t)(wt*32 + tj*16 + m)*264 + ko);
        #pragma unroll
        for (int ei = 0; ei < 4; ++ei)
            #pragma unroll
            for (int tj = 0; tj < 2; ++tj)
                acc2[ei][tj] = MFMA16(a[ei], bb[tj], acc2[ei][tj]);
    }

    // ---- bias + packed DIRECT global stores (no YB stage, no extra barrier)
    #pragma unroll
    for (int ei = 0; ei < 4; ++ei) {
        const int e0 = wf*64 + ei*16 + q*4;
        const float4 b2v = *reinterpret_cast<const float4*>(b2 + e0);
        #pragma unroll
        for (int tj = 0; tj < 2; ++tj) {
            const int token = wt*32 + tj*16 + m;
            float y0 = acc2[ei][tj][0] + b2v.x;
            float y1 = acc2[ei][tj][1] + b2v.y;
            float y2 = acc2[ei][tj][2] + b2v.z;
            float y3 = acc2[ei][tj][3] + b2v.w;
            *reinterpret_cast<uint2*>(yout + (tok0 + token)*FF + e0) =
                make_uint2(cvtpk(y0, y1), cvtpk(y2, y3));
        }
    }
}

// ------- per-(head,chunk) KV sums via MFMA -> bf16 TRANSPOSED [d][f] ---------
#define KVA_OFF 0
#define KVB_OFF (128*72)
#define KV_U16  (128*72 + 256*72)   // 55,296 B

__global__ __launch_bounds__(256) void kvsum_kernel(
    const u16* __restrict__ kphi, const float* __restrict__ v,
    u16* __restrict__ chunkT)
{
    __shared__ __align__(16) u16 kv[KV_U16];
    const int c = blockIdx.x, h = blockIdx.y, tid = threadIdx.x;
    const int w = tid >> 6, lane = tid & 63;
    const int m = lane & 15, q = lane >> 4;
    const int wr = w >> 1, wc = w & 1;
    const size_t tok0 = (size_t)h*SEQ + (size_t)c*CHK;
    const f32x4 zero4 = {0.f, 0.f, 0.f, 0.f};

    f32x4 acc[8][4];
    #pragma unroll
    for (int i = 0; i < 8; ++i)
        #pragma unroll
        for (int ct = 0; ct < 4; ++ct) acc[i][ct] = zero4;

    for (int tc = 0; tc < 2; ++tc) {
        {
            const u16* kb = kphi + (tok0 + tc*64)*FF + tid;
            #pragma unroll
            for (int tg = 0; tg < 8; ++tg) {
                u16 vals[8];
                #pragma unroll
                for (int tt = 0; tt < 8; ++tt)
                    vals[tt] = kb[(size_t)(tg*8 + tt)*FF];
                uint4 p;
                p.x = (u32)vals[0] | ((u32)vals[1] << 16);
                p.y = (u32)vals[2] | ((u32)vals[3] << 16);
                p.z = (u32)vals[4] | ((u32)vals[5] << 16);
                p.w = (u32)vals[6] | ((u32)vals[7] << 16);
                *reinterpret_cast<uint4*>(kv + KVB_OFF + tid*72 + tg*8) = p;
            }
        }
        {
            const int d  = tid & 127;
            const int th = tid >> 7;
            const float* vb = v + (tok0 + tc*64 + th*32)*DIM + d;
            #pragma unroll
            for (int tg = 0; tg < 4; ++tg) {
                float fv[8];
                #pragma unroll
                for (int tt = 0; tt < 8; ++tt)
                    fv[tt] = vb[(size_t)(tg*8 + tt)*DIM];
                uint4 p;
                p.x = cvtpk(fv[0], fv[1]);
                p.y = cvtpk(fv[2], fv[3]);
                p.z = cvtpk(fv[4], fv[5]);
                p.w = cvtpk(fv[6], fv[7]);
                *reinterpret_cast<uint4*>(kv + KVA_OFF + d*72 + th*32 + tg*8) = p;
            }
        }
        __syncthreads();

        #pragma unroll
        for (int k2 = 0; k2 < 2; ++k2) {
            const int ko = k2*32 + q*8;
            s16x8 a[8], bb[4];
            #pragma unroll
            for (int i = 0; i < 8; ++i)
                a[i] = *reinterpret_cast<const s16x8*>(kv + KVB_OFF + (wc*128 + i*16 + m)*72 + ko);
            #pragma unroll
            for (int ct = 0; ct < 4; ++ct)
                bb[ct] = *reinterpret_cast<const s16x8*>(kv + KVA_OFF + (wr*64 + ct*16 + m)*72 + ko);
            #pragma unroll
            for (int i = 0; i < 8; ++i)
                #pragma unroll
                for (int ct = 0; ct < 4; ++ct)
                    acc[i][ct] = MFMA16(a[i], bb[ct], acc[i][ct]);
        }
        __syncthreads();
    }

    u16* outp = chunkT + (size_t)(h*NC + c)*SLOT;
    #pragma unroll
    for (int i = 0; i < 8; ++i) {
        const int f0 = wc*128 + i*16 + q*4;
        #pragma unroll
        for (int ct = 0; ct < 4; ++ct) {
            const int d = wr*64 + ct*16 + m;
            *reinterpret_cast<uint2*>(outp + (size_t)d*FF + f0) =
                make_uint2(cvtpk(acc[i][ct][0], acc[i][ct][1]),
                           cvtpk(acc[i][ct][2], acc[i][ct][3]));
        }
    }
}

// ---------------- elementwise scan over chunks (layout-agnostic, proven) -----
__global__ __launch_bounds__(256) void scan_kernel(
    u16* __restrict__ chunkT, u16* __restrict__ sufT)
{
    const int g = blockIdx.x * 256 + threadIdx.x;
    const int h = g >> 12;
    const int e = (g & 4095) * 8;
    u16* base  = chunkT + (size_t)h*NC*SLOT + e;
    u16* sbase = sufT   + (size_t)h*NC*SLOT + e;

    float tot[8];
    #pragma unroll
    for (int i = 0; i < 8; ++i) tot[i] = 0.f;
    for (int c = 0; c < NC; ++c) {
        uint4 r = *reinterpret_cast<const uint4*>(base + (size_t)c*SLOT);
        tot[0] += __uint_as_float(r.x << 16);
        tot[1] += __uint_as_float(r.x & 0xffff0000u);
        tot[2] += __uint_as_float(r.y << 16);
        tot[3] += __uint_as_float(r.y & 0xffff0000u);
        tot[4] += __uint_as_float(r.z << 16);
        tot[5] += __uint_as_float(r.z & 0xffff0000u);
        tot[6] += __uint_as_float(r.w << 16);
        tot[7] += __uint_as_float(r.w & 0xffff0000u);
    }
    float run[8];
    #pragma unroll
    for (int i = 0; i < 8; ++i) run[i] = 0.f;
    for (int c = 0; c < NC; ++c) {
        uint4 r = *reinterpret_cast<const uint4*>(base + (size_t)c*SLOT);
        float old[8];
        old[0] = __uint_as_float(r.x << 16);
        old[1] = __uint_as_float(r.x & 0xffff0000u);
        old[2] = __uint_as_float(r.y << 16);
        old[3] = __uint_as_float(r.y & 0xffff0000u);
        old[4] = __uint_as_float(r.z << 16);
        old[5] = __uint_as_float(r.z & 0xffff0000u);
        old[6] = __uint_as_float(r.w << 16);
        old[7] = __uint_as_float(r.w & 0xffff0000u);
        uint4 wp, wsuf;
        wp.x = cvtpk(run[0], run[1]);
        wp.y = cvtpk(run[2], run[3]);
        wp.z = cvtpk(run[4], run[5]);
        wp.w = cvtpk(run[6], run[7]);
        *reinterpret_cast<uint4*>(base + (size_t)c*SLOT) = wp;
        #pragma unroll
        for (int i = 0; i < 8; ++i) run[i] += old[i];
        float sf[8];
        #pragma unroll
        for (int i = 0; i < 8; ++i) sf[i] = tot[i] - run[i];
        wsuf.x = cvtpk(sf[0], sf[1]);
        wsuf.y = cvtpk(sf[2], sf[3]);
        wsuf.z = cvtpk(sf[4], sf[5]);
        wsuf.w = cvtpk(sf[6], sf[7]);
        *reinterpret_cast<uint4*>(sbase + (size_t)c*SLOT) = wsuf;
    }
}

// ------- output: all-MFMA, LDS-staged B streams (read once, coalesced) ------
#define VT_OFF 0
#define SF_OFF (128*136)
#define WB_OFF (2*128*136)
#define OARENA_U16 (2*128*136 + 128*264)   // 68,608 u16 = 137,216 B

__global__ __launch_bounds__(512, 2) void out_kernel(
    const u16* __restrict__ qphi, const u16* __restrict__ kphi,
    const float* __restrict__ v,
    const u16* __restrict__ prefT, const u16* __restrict__ sufT,
    float* __restrict__ out)
{
    __shared__ __align__(16) u16 arena[OARENA_U16];
    const int c = blockIdx.x, h = blockIdx.y;
    const int tid = threadIdx.x;
    const int w = tid >> 6, lane = tid & 63;
    const int m = lane & 15, q = lane >> 4;
    const size_t tok0 = (size_t)h*SEQ + (size_t)c*CHK;
    const u16* qbase = qphi + tok0*FF;
    const int R = w*16;
    const int rowA = R + m;
    const f32x4 zero4 = {0.f, 0.f, 0.f, 0.f};

    // ---- stage VT (v^T bf16 [d][j], stride 136) ----------------------------
    {
        const int d  = tid & 127;
        const int j0 = (tid >> 7) * 8;
        const float* vb = v + tok0*DIM + d;
        #pragma unroll
        for (int jb = 0; jb < 4; ++jb) {
            const int jbase = jb*32 + j0;
            float vals[8];
            #pragma unroll
            for (int t = 0; t < 8; ++t) vals[t] = vb[(size_t)(jbase + t)*DIM];
            uint4 p;
            p.x = cvtpk(vals[0], vals[1]);
            p.y = cvtpk(vals[2], vals[3]);
            p.z = cvtpk(vals[4], vals[5]);
            p.w = cvtpk(vals[6], vals[7]);
            *reinterpret_cast<uint4*>(arena + VT_OFF + d*136 + jbase) = p;
        }
    }
    // ---- stage kphi -> WB (coalesced uint4, stride 264 = 33 uint4) ---------
    {
        const uint4* src = reinterpret_cast<const uint4*>(kphi + tok0*FF);
        uint4* dst = reinterpret_cast<uint4*>(arena + WB_OFF);
        for (int i = tid; i < 128*32; i += 512) {
            int row = i >> 5, cc = i & 31;
            dst[row*33 + cc] = src[i];
        }
    }
    __syncthreads();   // barrier1: VT + kphi visible

    s16x8 qreg[8];
    #pragma unroll
    for (int kk = 0; kk < 8; ++kk)
        qreg[kk] = *reinterpret_cast<const s16x8*>(qbase + (size_t)rowA*FF + kk*32 + q*8);

    // ---- phase 1: S = Qphi Kphi^T (B from WB LDS), write bf16 SF -----------
    {
        f32x4 sacc[8];
        #pragma unroll
        for (int ct = 0; ct < 8; ++ct) sacc[ct] = zero4;
        for (int kk = 0; kk < 8; ++kk) {
            const int ko = kk*32 + q*8;
            #pragma unroll
            for (int ct = 0; ct < 8; ++ct) {
                s16x8 b = *reinterpret_cast<const s16x8*>(arena + WB_OFF + (size_t)(ct*16 + m)*264 + ko);
                sacc[ct] = MFMA16(qreg[kk], b, sacc[ct]);
            }
        }
        #pragma unroll
        for (int ct = 0; ct < 8; ++ct) {
            #pragma unroll
            for (int reg = 0; reg < 4; ++reg)
                arena[SF_OFF + (size_t)(R + q*4 + reg)*136 + (ct*16 + m)] = f2bf(sacc[ct][reg]);
        }
    }
    __syncthreads();   // barrier2: SF visible, WB (kphi) reads done

    f32x4 accA[8], accB[8];
    #pragma unroll
    for (int ct = 0; ct < 8; ++ct) { accA[ct] = zero4; accB[ct] = zero4; }

    uint4 stg[8];
    {
        const uint4* src = reinterpret_cast<const uint4*>(prefT + (size_t)(h*NC + c)*SLOT);
        #pragma unroll
        for (int i = 0; i < 8; ++i) stg[i] = src[tid + i*512];
    }

    // ---- phase 2: intra via triangular-masked MFMA GEMMs (SF x VT) ---------
    #pragma unroll
    for (int kk = 0; kk < 4; ++kk) {
        const int ko = kk*32 + q*8;
        s16x8 b[8];
        #pragma unroll
        for (int ct = 0; ct < 8; ++ct)
            b[ct] = *reinterpret_cast<const s16x8*>(arena + VT_OFF + (size_t)(ct*16 + m)*136 + ko);
        const bool anyLow  = (kk*32       <= R + 15);
        const bool lowFull = (kk*32 + 31  <= R);
        const bool anyUp   = (kk*32 + 31  >= R);
        const bool upFull  = (kk*32       >= R + 16);
        s16x8 a = *reinterpret_cast<const s16x8*>(arena + SF_OFF + (size_t)rowA*136 + ko);
        if (anyLow) {
            s16x8 aL;
            if (lowFull) aL = a;
            else {
                #pragma unroll
                for (int e = 0; e < 8; ++e)
                    aL[e] = (kk*32 + q*8 + e <= rowA) ? a[e] : (short)0;
            }
            #pragma unroll
            for (int ct = 0; ct < 8; ++ct)
                accA[ct] = MFMA16(aL, b[ct], accA[ct]);
        }
        if (anyUp) {
            s16x8 aU;
            if (upFull) aU = a;
            else {
                #pragma unroll
                for (int e = 0; e < 8; ++e)
                    aU[e] = (kk*32 + q*8 + e >= rowA) ? a[e] : (short)0;
            }
            #pragma unroll
            for (int ct = 0; ct < 8; ++ct)
                accB[ct] = MFMA16(aU, b[ct], accB[ct]);
        }
    }

    {
        uint4* dst = reinterpret_cast<uint4*>(arena + WB_OFF);
        #pragma unroll
        for (int i = 0; i < 8; ++i) {
            int idx = tid + i*512;
            int row = idx >> 5, cc = idx & 31;
            dst[row*33 + cc] = stg[i];
        }
    }
    __syncthreads();   // barrier3: pref visible, VT/SF reads done

    {
        const uint4* src = reinterpret_cast<const uint4*>(sufT + (size_t)(h*NC + c)*SLOT);
        #pragma unroll
        for (int i = 0; i < 8; ++i) stg[i] = src[tid + i*512];
    }

    // ---- phase 3a: accA += Q . pref (B from WB) ----------------------------
    for (int kk = 0; kk < 8; ++kk) {
        const int ko = kk*32 + q*8;
        #pragma unroll
        for (int nt = 0; nt < 8; ++nt) {
            s16x8 bp = *reinterpret_cast<const s16x8*>(arena + WB_OFF + (size_t)(nt*16 + m)*264 + ko);
            accA[nt] = MFMA16(qreg[kk], bp, accA[nt]);
        }
    }

    {
        uint4* dst = reinterpret_cast<uint4*>(arena);
        #pragma unroll
        for (int i = 0; i < 8; ++i) {
            int idx = tid + i*512;
            int row = idx >> 5, cc = idx & 31;
            dst[row*33 + cc] = stg[i];
        }
    }
    __syncthreads();   // barrier4: suf visible, WB (pref) reads done

    // ---- phase 3b: accB += Q . suf -----------------------------------------
    for (int kk = 0; kk < 8; ++kk) {
        const int ko = kk*32 + q*8;
        #pragma unroll
        for (int nt = 0; nt < 8; ++nt) {
            s16x8 bs = *reinterpret_cast<const s16x8*>(arena + (size_t)(nt*16 + m)*264 + ko);
            accB[nt] = MFMA16(qreg[kk], bs, accB[nt]);
        }
    }

    // ---- epilogue ----------------------------------------------------------
    #pragma unroll
    for (int reg = 0; reg < 4; ++reg) {
        const int row = R + q*4 + reg;
        const int pos = c*CHK + row;
        const float ia = 1.0f / (float)(pos + 1);
        const float ib = 1.0f / (float)(SEQ - pos);
        float* orow = out + (tok0 + (size_t)row)*DIM;
        #pragma unroll
        for (int ct = 0; ct < 8; ++ct)
            orow[ct*16 + m] = accA[ct][reg]*ia + accB[ct][reg]*ib;
    }
}

extern "C" void kernel_launch(void* const* d_in, const int* in_sizes, int n_in,
                              void* d_out, int out_size, void* d_ws, size_t ws_size,
                              hipStream_t stream) {
    const float* q  = (const float*)d_in[0];
    const float* k  = (const float*)d_in[1];
    const float* v  = (const float*)d_in[2];
    const float* w1 = (const float*)d_in[3];
    const float* b1 = (const float*)d_in[4];
    const float* w2 = (const float*)d_in[5];
    const float* b2 = (const float*)d_in[6];
    float* out = (float*)d_out;

    char* ws = (char*)d_ws;
    const size_t phiBytes = (size_t)BH*SEQ*FF*sizeof(u16);   // 50,331,648
    u16* qphi   = (u16*)ws;
    u16* kphi   = (u16*)(ws + phiBytes);
    u16* chunkT = (u16*)(ws + 2*phiBytes);   // becomes prefT in-place after scan
    u16* sufT   = (u16*)(ws + 3*phiBytes);
    u16* w1t    = (u16*)(ws + 4*phiBytes);               // 256*136*2 = 69,632 B
    u16* w2t    = w1t + 256*136;                         // 256*264*2 = 135,168 B

    prep_kernel<<<dim3(100), 256, 0, stream>>>(w1, w2, w1t, w2t);
    phi_fused_kernel<<<dim3(2*(BH*SEQ)/PTOK), 512, 0, stream>>>(q, k, b1, b2, w1t, w2t, qphi, kphi);
    kvsum_kernel<<<dim3(NC, BH), 256, 0, stream>>>(kphi, v, chunkT);
    scan_kernel<<<dim3(384), 256, 0, stream>>>(chunkT, sufT);
    out_kernel<<<dim3(NC, BH), 512, 0, stream>>>(qphi, kphi, v, chunkT, sufT, out);
}

// Round 9
// 386.906 us; speedup vs baseline: 1.0604x; 1.0604x over previous
//
#include <hip/hip_runtime.h>

#define BH  24
#define SEQ 4096
#define DIM 128
#define FF  256
#define CHK 128
#define NC  32
#define SLOT (FF*DIM)

typedef unsigned short u16;
typedef unsigned int   u32;
typedef short  s16x8 __attribute__((ext_vector_type(8)));
typedef float  f32x4 __attribute__((ext_vector_type(4)));

#define MFMA16(a,b,c) __builtin_amdgcn_mfma_f32_16x16x32_bf16(a,b,c,0,0,0)

static __device__ __forceinline__ float bf2f(u16 u) {
    return __uint_as_float(((u32)u) << 16);
}
static __device__ __forceinline__ u16 f2bf(float f) {
    u32 u = __float_as_uint(f);
    u += 0x7fffu + ((u >> 16) & 1u);
    return (u16)(u >> 16);
}
// packed RNE f32x2 -> bf16x2 (lo in [15:0], hi in [31:16])
static __device__ __forceinline__ u32 cvtpk(float lo, float hi) {
    u32 r;
    asm("v_cvt_pk_bf16_f32 %0, %1, %2" : "=v"(r) : "v"(lo), "v"(hi));
    return r;
}

// ---------------- weight prep: transposed, padded, bf16 ----------------------
__global__ __launch_bounds__(256) void prep_kernel(
    const float* __restrict__ w1, const float* __restrict__ w2,
    u16* __restrict__ w1t, u16* __restrict__ w2t)
{
    int idx = blockIdx.x * 256 + threadIdx.x;
    int stride = gridDim.x * 256;
    for (int i = idx; i < 256*136; i += stride) {
        int f = i / 136, d = i - f*136;
        w1t[i] = (d < 128) ? f2bf(w1[d*FF + f]) : (u16)0;
    }
    for (int i = idx; i < 256*264; i += stride) {
        int e = i / 264, f = i - e*264;
        w2t[i] = (f < 256) ? f2bf(w2[f*FF + e]) : (u16)0;
    }
}

// ---------------- fused phi via MFMA: y = silu(x@W1+b1)@W2 + b2 --------------
// R7-proven structure (133 us): 512 thr, PTOK=64, weights from global,
// C[token][f] orientation, staged coalesced Y store.  NEW: SiLU division ->
// v_rcp_f32 (kills the ~10-instr div sequence x32/thread), cvt_pk XS pack.
#define PTOK 64
#define XS_OFF   0
#define HS_OFF   0
#define YB_OFF   0
#define ARENA_U16 16896   // 33,792 B

__global__ __launch_bounds__(512) void phi_fused_kernel(
    const float* __restrict__ xq, const float* __restrict__ xk,
    const float* __restrict__ b1, const float* __restrict__ b2,
    const u16* __restrict__ w1t, const u16* __restrict__ w2t,
    u16* __restrict__ yq, u16* __restrict__ yk)
{
    __shared__ __align__(16) u16 arena[ARENA_U16];
    const int tid = threadIdx.x;
    int b = blockIdx.x;
    const int nB = (BH*SEQ)/PTOK;   // 1536
    const float* xin; u16* yout;
    if (b < nB) { xin = xq; yout = yq; }
    else        { xin = xk; yout = yk; b -= nB; }
    const size_t tok0 = (size_t)b * PTOK;

    const int w = tid >> 6, lane = tid & 63;
    const int m = lane & 15, q = lane >> 4;
    const int wr = w >> 2, wc = w & 3;
    const f32x4 zero4 = {0.f, 0.f, 0.f, 0.f};

    // ---- stage XS (fp32 -> bf16 via cvt_pk), [64][136] ---------------------
    {
        const float4* xsrc = reinterpret_cast<const float4*>(xin + tok0*DIM);
        for (int i = tid; i < PTOK*DIM/4; i += 512) {
            int row = i >> 5, c4 = i & 31;
            float4 xv = xsrc[i];
            *reinterpret_cast<uint2*>(arena + XS_OFF + row*136 + c4*4) =
                make_uint2(cvtpk(xv.x, xv.y), cvtpk(xv.z, xv.w));
        }
    }
    __syncthreads();   // sync1: XS visible

    // ---- GEMM1: H[64][256] = XS @ W1 (B-frags from global w1t), K=128 ------
    f32x4 acc[2][4];
    #pragma unroll
    for (int i = 0; i < 2; ++i)
        #pragma unroll
        for (int ct = 0; ct < 4; ++ct) acc[i][ct] = zero4;

    #pragma unroll
    for (int kk = 0; kk < 4; ++kk) {
        int ko = kk*32 + q*8;
        s16x8 a[2], bb[4];
        #pragma unroll
        for (int ct = 0; ct < 4; ++ct)
            bb[ct] = *reinterpret_cast<const s16x8*>(w1t + (size_t)(wc*64 + ct*16 + m)*136 + ko);
        #pragma unroll
        for (int i = 0; i < 2; ++i)
            a[i] = *reinterpret_cast<const s16x8*>(arena + XS_OFF + (wr*32 + i*16 + m)*136 + ko);
        #pragma unroll
        for (int i = 0; i < 2; ++i)
            #pragma unroll
            for (int ct = 0; ct < 4; ++ct)
                acc[i][ct] = MFMA16(a[i], bb[ct], acc[i][ct]);
    }
    __syncthreads();   // sync2: XS reads done; HS overwrites that space

    // ---- bias + SiLU (rcp approx), write HS bf16 [64][264] -----------------
    {
        float b1v[4];
        #pragma unroll
        for (int ct = 0; ct < 4; ++ct) b1v[ct] = b1[wc*64 + ct*16 + m];
        #pragma unroll
        for (int i = 0; i < 2; ++i) {
            #pragma unroll
            for (int ct = 0; ct < 4; ++ct) {
                #pragma unroll
                for (int reg = 0; reg < 4; ++reg) {
                    float h = acc[i][ct][reg] + b1v[ct];
                    h = h * __builtin_amdgcn_rcpf(1.0f + __expf(-h));
                    arena[HS_OFF + (size_t)(wr*32 + i*16 + q*4 + reg)*264 + (wc*64 + ct*16 + m)] = f2bf(h);
                }
            }
        }
    }
    __syncthreads();   // sync3: HS visible

    // ---- GEMM2: Y[64][256] = HS @ W2 (B-frags from global w2t), K=256 ------
    f32x4 acc2[2][4];
    #pragma unroll
    for (int i = 0; i < 2; ++i)
        #pragma unroll
        for (int ct = 0; ct < 4; ++ct) acc2[i][ct] = zero4;

    #pragma unroll
    for (int kk = 0; kk < 8; ++kk) {
        int ko = kk*32 + q*8;
        s16x8 a[2], bb[4];
        #pragma unroll
        for (int ct = 0; ct < 4; ++ct)
            bb[ct] = *reinterpret_cast<const s16x8*>(w2t + (size_t)(wc*64 + ct*16 + m)*264 + ko);
        #pragma unroll
        for (int i = 0; i < 2; ++i)
            a[i] = *reinterpret_cast<const s16x8*>(arena + HS_OFF + (size_t)(wr*32 + i*16 + m)*264 + ko);
        #pragma unroll
        for (int i = 0; i < 2; ++i)
            #pragma unroll
            for (int ct = 0; ct < 4; ++ct)
                acc2[i][ct] = MFMA16(a[i], bb[ct], acc2[i][ct]);
    }
    __syncthreads();   // sync4: HS reads done; YB overwrites

    // ---- bias, Y -> LDS, coalesced uint4 store -----------------------------
    {
        float b2v[4];
        #pragma unroll
        for (int ct = 0; ct < 4; ++ct) b2v[ct] = b2[wc*64 + ct*16 + m];
        #pragma unroll
        for (int i = 0; i < 2; ++i) {
            #pragma unroll
            for (int ct = 0; ct < 4; ++ct) {
                #pragma unroll
                for (int reg = 0; reg < 4; ++reg) {
                    float y = acc2[i][ct][reg] + b2v[ct];
                    arena[YB_OFF + (size_t)(wr*32 + i*16 + q*4 + reg)*264 + (wc*64 + ct*16 + m)] = f2bf(y);
                }
            }
        }
    }
    __syncthreads();   // sync5: YB visible
    {
        uint4* dst = reinterpret_cast<uint4*>(yout + tok0*FF);
        const uint4* srcy = reinterpret_cast<const uint4*>(arena + YB_OFF);
        for (int i = tid; i < PTOK*32; i += 512) {
            int row = i >> 5, c = i & 31;
            dst[i] = srcy[row*33 + c];
        }
    }
}

// ------- per-(head,chunk) KV sums via MFMA -> bf16 TRANSPOSED [d][f] ---------
#define KVA_OFF 0
#define KVB_OFF (128*72)
#define KV_U16  (128*72 + 256*72)   // 55,296 B

__global__ __launch_bounds__(256) void kvsum_kernel(
    const u16* __restrict__ kphi, const float* __restrict__ v,
    u16* __restrict__ chunkT)
{
    __shared__ __align__(16) u16 kv[KV_U16];
    const int c = blockIdx.x, h = blockIdx.y, tid = threadIdx.x;
    const int w = tid >> 6, lane = tid & 63;
    const int m = lane & 15, q = lane >> 4;
    const int wr = w >> 1, wc = w & 1;
    const size_t tok0 = (size_t)h*SEQ + (size_t)c*CHK;
    const f32x4 zero4 = {0.f, 0.f, 0.f, 0.f};

    f32x4 acc[8][4];
    #pragma unroll
    for (int i = 0; i < 8; ++i)
        #pragma unroll
        for (int ct = 0; ct < 4; ++ct) acc[i][ct] = zero4;

    for (int tc = 0; tc < 2; ++tc) {
        {
            const u16* kb = kphi + (tok0 + tc*64)*FF + tid;
            #pragma unroll
            for (int tg = 0; tg < 8; ++tg) {
                u16 vals[8];
                #pragma unroll
                for (int tt = 0; tt < 8; ++tt)
                    vals[tt] = kb[(size_t)(tg*8 + tt)*FF];
                uint4 p;
                p.x = (u32)vals[0] | ((u32)vals[1] << 16);
                p.y = (u32)vals[2] | ((u32)vals[3] << 16);
                p.z = (u32)vals[4] | ((u32)vals[5] << 16);
                p.w = (u32)vals[6] | ((u32)vals[7] << 16);
                *reinterpret_cast<uint4*>(kv + KVB_OFF + tid*72 + tg*8) = p;
            }
        }
        {
            const int d  = tid & 127;
            const int th = tid >> 7;
            const float* vb = v + (tok0 + tc*64 + th*32)*DIM + d;
            #pragma unroll
            for (int tg = 0; tg < 4; ++tg) {
                float fv[8];
                #pragma unroll
                for (int tt = 0; tt < 8; ++tt)
                    fv[tt] = vb[(size_t)(tg*8 + tt)*DIM];
                uint4 p;
                p.x = cvtpk(fv[0], fv[1]);
                p.y = cvtpk(fv[2], fv[3]);
                p.z = cvtpk(fv[4], fv[5]);
                p.w = cvtpk(fv[6], fv[7]);
                *reinterpret_cast<uint4*>(kv + KVA_OFF + d*72 + th*32 + tg*8) = p;
            }
        }
        __syncthreads();

        #pragma unroll
        for (int k2 = 0; k2 < 2; ++k2) {
            const int ko = k2*32 + q*8;
            s16x8 a[8], bb[4];
            #pragma unroll
            for (int i = 0; i < 8; ++i)
                a[i] = *reinterpret_cast<const s16x8*>(kv + KVB_OFF + (wc*128 + i*16 + m)*72 + ko);
            #pragma unroll
            for (int ct = 0; ct < 4; ++ct)
                bb[ct] = *reinterpret_cast<const s16x8*>(kv + KVA_OFF + (wr*64 + ct*16 + m)*72 + ko);
            #pragma unroll
            for (int i = 0; i < 8; ++i)
                #pragma unroll
                for (int ct = 0; ct < 4; ++ct)
                    acc[i][ct] = MFMA16(a[i], bb[ct], acc[i][ct]);
        }
        __syncthreads();
    }

    u16* outp = chunkT + (size_t)(h*NC + c)*SLOT;
    #pragma unroll
    for (int i = 0; i < 8; ++i) {
        const int f0 = wc*128 + i*16 + q*4;
        #pragma unroll
        for (int ct = 0; ct < 4; ++ct) {
            const int d = wr*64 + ct*16 + m;
            *reinterpret_cast<uint2*>(outp + (size_t)d*FF + f0) =
                make_uint2(cvtpk(acc[i][ct][0], acc[i][ct][1]),
                           cvtpk(acc[i][ct][2], acc[i][ct][3]));
        }
    }
}

// ---------------- elementwise scan over chunks (layout-agnostic, proven) -----
__global__ __launch_bounds__(256) void scan_kernel(
    u16* __restrict__ chunkT, u16* __restrict__ sufT)
{
    const int g = blockIdx.x * 256 + threadIdx.x;
    const int h = g >> 12;
    const int e = (g & 4095) * 8;
    u16* base  = chunkT + (size_t)h*NC*SLOT + e;
    u16* sbase = sufT   + (size_t)h*NC*SLOT + e;

    float tot[8];
    #pragma unroll
    for (int i = 0; i < 8; ++i) tot[i] = 0.f;
    for (int c = 0; c < NC; ++c) {
        uint4 r = *reinterpret_cast<const uint4*>(base + (size_t)c*SLOT);
        tot[0] += __uint_as_float(r.x << 16);
        tot[1] += __uint_as_float(r.x & 0xffff0000u);
        tot[2] += __uint_as_float(r.y << 16);
        tot[3] += __uint_as_float(r.y & 0xffff0000u);
        tot[4] += __uint_as_float(r.z << 16);
        tot[5] += __uint_as_float(r.z & 0xffff0000u);
        tot[6] += __uint_as_float(r.w << 16);
        tot[7] += __uint_as_float(r.w & 0xffff0000u);
    }
    float run[8];
    #pragma unroll
    for (int i = 0; i < 8; ++i) run[i] = 0.f;
    for (int c = 0; c < NC; ++c) {
        uint4 r = *reinterpret_cast<const uint4*>(base + (size_t)c*SLOT);
        float old[8];
        old[0] = __uint_as_float(r.x << 16);
        old[1] = __uint_as_float(r.x & 0xffff0000u);
        old[2] = __uint_as_float(r.y << 16);
        old[3] = __uint_as_float(r.y & 0xffff0000u);
        old[4] = __uint_as_float(r.z << 16);
        old[5] = __uint_as_float(r.z & 0xffff0000u);
        old[6] = __uint_as_float(r.w << 16);
        old[7] = __uint_as_float(r.w & 0xffff0000u);
        uint4 wp, wsuf;
        wp.x = cvtpk(run[0], run[1]);
        wp.y = cvtpk(run[2], run[3]);
        wp.z = cvtpk(run[4], run[5]);
        wp.w = cvtpk(run[6], run[7]);
        *reinterpret_cast<uint4*>(base + (size_t)c*SLOT) = wp;
        #pragma unroll
        for (int i = 0; i < 8; ++i) run[i] += old[i];
        float sf[8];
        #pragma unroll
        for (int i = 0; i < 8; ++i) sf[i] = tot[i] - run[i];
        wsuf.x = cvtpk(sf[0], sf[1]);
        wsuf.y = cvtpk(sf[2], sf[3]);
        wsuf.z = cvtpk(sf[4], sf[5]);
        wsuf.w = cvtpk(sf[6], sf[7]);
        *reinterpret_cast<uint4*>(sbase + (size_t)c*SLOT) = wsuf;
    }
}

// ------- output: all-MFMA, LDS-staged B streams (read once, coalesced) ------
#define VT_OFF 0
#define SF_OFF (128*136)
#define WB_OFF (2*128*136)
#define OARENA_U16 (2*128*136 + 128*264)   // 68,608 u16 = 137,216 B

__global__ __launch_bounds__(512, 2) void out_kernel(
    const u16* __restrict__ qphi, const u16* __restrict__ kphi,
    const float* __restrict__ v,
    const u16* __restrict__ prefT, const u16* __restrict__ sufT,
    float* __restrict__ out)
{
    __shared__ __align__(16) u16 arena[OARENA_U16];
    const int c = blockIdx.x, h = blockIdx.y;
    const int tid = threadIdx.x;
    const int w = tid >> 6, lane = tid & 63;
    const int m = lane & 15, q = lane >> 4;
    const size_t tok0 = (size_t)h*SEQ + (size_t)c*CHK;
    const u16* qbase = qphi + tok0*FF;
    const int R = w*16;
    const int rowA = R + m;
    const f32x4 zero4 = {0.f, 0.f, 0.f, 0.f};

    // ---- stage VT (v^T bf16 [d][j], stride 136) ----------------------------
    {
        const int d  = tid & 127;
        const int j0 = (tid >> 7) * 8;
        const float* vb = v + tok0*DIM + d;
        #pragma unroll
        for (int jb = 0; jb < 4; ++jb) {
            const int jbase = jb*32 + j0;
            float vals[8];
            #pragma unroll
            for (int t = 0; t < 8; ++t) vals[t] = vb[(size_t)(jbase + t)*DIM];
            uint4 p;
            p.x = cvtpk(vals[0], vals[1]);
            p.y = cvtpk(vals[2], vals[3]);
            p.z = cvtpk(vals[4], vals[5]);
            p.w = cvtpk(vals[6], vals[7]);
            *reinterpret_cast<uint4*>(arena + VT_OFF + d*136 + jbase) = p;
        }
    }
    // ---- stage kphi -> WB (coalesced uint4, stride 264 = 33 uint4) ---------
    {
        const uint4* src = reinterpret_cast<const uint4*>(kphi + tok0*FF);
        uint4* dst = reinterpret_cast<uint4*>(arena + WB_OFF);
        for (int i = tid; i < 128*32; i += 512) {
            int row = i >> 5, cc = i & 31;
            dst[row*33 + cc] = src[i];
        }
    }
    __syncthreads();   // barrier1: VT + kphi visible

    s16x8 qreg[8];
    #pragma unroll
    for (int kk = 0; kk < 8; ++kk)
        qreg[kk] = *reinterpret_cast<const s16x8*>(qbase + (size_t)rowA*FF + kk*32 + q*8);

    // ---- phase 1: S = Qphi Kphi^T (B from WB LDS), write bf16 SF -----------
    {
        f32x4 sacc[8];
        #pragma unroll
        for (int ct = 0; ct < 8; ++ct) sacc[ct] = zero4;
        for (int kk = 0; kk < 8; ++kk) {
            const int ko = kk*32 + q*8;
            #pragma unroll
            for (int ct = 0; ct < 8; ++ct) {
                s16x8 b = *reinterpret_cast<const s16x8*>(arena + WB_OFF + (size_t)(ct*16 + m)*264 + ko);
                sacc[ct] = MFMA16(qreg[kk], b, sacc[ct]);
            }
        }
        #pragma unroll
        for (int ct = 0; ct < 8; ++ct) {
            #pragma unroll
            for (int reg = 0; reg < 4; ++reg)
                arena[SF_OFF + (size_t)(R + q*4 + reg)*136 + (ct*16 + m)] = f2bf(sacc[ct][reg]);
        }
    }
    __syncthreads();   // barrier2: SF visible, WB (kphi) reads done

    f32x4 accA[8], accB[8];
    #pragma unroll
    for (int ct = 0; ct < 8; ++ct) { accA[ct] = zero4; accB[ct] = zero4; }

    uint4 stg[8];
    {
        const uint4* src = reinterpret_cast<const uint4*>(prefT + (size_t)(h*NC + c)*SLOT);
        #pragma unroll
        for (int i = 0; i < 8; ++i) stg[i] = src[tid + i*512];
    }

    // ---- phase 2: intra via triangular-masked MFMA GEMMs (SF x VT) ---------
    #pragma unroll
    for (int kk = 0; kk < 4; ++kk) {
        const int ko = kk*32 + q*8;
        s16x8 b[8];
        #pragma unroll
        for (int ct = 0; ct < 8; ++ct)
            b[ct] = *reinterpret_cast<const s16x8*>(arena + VT_OFF + (size_t)(ct*16 + m)*136 + ko);
        const bool anyLow  = (kk*32       <= R + 15);
        const bool lowFull = (kk*32 + 31  <= R);
        const bool anyUp   = (kk*32 + 31  >= R);
        const bool upFull  = (kk*32       >= R + 16);
        s16x8 a = *reinterpret_cast<const s16x8*>(arena + SF_OFF + (size_t)rowA*136 + ko);
        if (anyLow) {
            s16x8 aL;
            if (lowFull) aL = a;
            else {
                #pragma unroll
                for (int e = 0; e < 8; ++e)
                    aL[e] = (kk*32 + q*8 + e <= rowA) ? a[e] : (short)0;
            }
            #pragma unroll
            for (int ct = 0; ct < 8; ++ct)
                accA[ct] = MFMA16(aL, b[ct], accA[ct]);
        }
        if (anyUp) {
            s16x8 aU;
            if (upFull) aU = a;
            else {
                #pragma unroll
                for (int e = 0; e < 8; ++e)
                    aU[e] = (kk*32 + q*8 + e >= rowA) ? a[e] : (short)0;
            }
            #pragma unroll
            for (int ct = 0; ct < 8; ++ct)
                accB[ct] = MFMA16(aU, b[ct], accB[ct]);
        }
    }

    {
        uint4* dst = reinterpret_cast<uint4*>(arena + WB_OFF);
        #pragma unroll
        for (int i = 0; i < 8; ++i) {
            int idx = tid + i*512;
            int row = idx >> 5, cc = idx & 31;
            dst[row*33 + cc] = stg[i];
        }
    }
    __syncthreads();   // barrier3: pref visible, VT/SF reads done

    {
        const uint4* src = reinterpret_cast<const uint4*>(sufT + (size_t)(h*NC + c)*SLOT);
        #pragma unroll
        for (int i = 0; i < 8; ++i) stg[i] = src[tid + i*512];
    }

    // ---- phase 3a: accA += Q . pref (B from WB) ----------------------------
    for (int kk = 0; kk < 8; ++kk) {
        const int ko = kk*32 + q*8;
        #pragma unroll
        for (int nt = 0; nt < 8; ++nt) {
            s16x8 bp = *reinterpret_cast<const s16x8*>(arena + WB_OFF + (size_t)(nt*16 + m)*264 + ko);
            accA[nt] = MFMA16(qreg[kk], bp, accA[nt]);
        }
    }

    {
        uint4* dst = reinterpret_cast<uint4*>(arena);
        #pragma unroll
        for (int i = 0; i < 8; ++i) {
            int idx = tid + i*512;
            int row = idx >> 5, cc = idx & 31;
            dst[row*33 + cc] = stg[i];
        }
    }
    __syncthreads();   // barrier4: suf visible, WB (pref) reads done

    // ---- phase 3b: accB += Q . suf -----------------------------------------
    for (int kk = 0; kk < 8; ++kk) {
        const int ko = kk*32 + q*8;
        #pragma unroll
        for (int nt = 0; nt < 8; ++nt) {
            s16x8 bs = *reinterpret_cast<const s16x8*>(arena + (size_t)(nt*16 + m)*264 + ko);
            accB[nt] = MFMA16(qreg[kk], bs, accB[nt]);
        }
    }

    // ---- epilogue ----------------------------------------------------------
    #pragma unroll
    for (int reg = 0; reg < 4; ++reg) {
        const int row = R + q*4 + reg;
        const int pos = c*CHK + row;
        const float ia = 1.0f / (float)(pos + 1);
        const float ib = 1.0f / (float)(SEQ - pos);
        float* orow = out + (tok0 + (size_t)row)*DIM;
        #pragma unroll
        for (int ct = 0; ct < 8; ++ct)
            orow[ct*16 + m] = accA[ct][reg]*ia + accB[ct][reg]*ib;
    }
}

extern "C" void kernel_launch(void* const* d_in, const int* in_sizes, int n_in,
                              void* d_out, int out_size, void* d_ws, size_t ws_size,
                              hipStream_t stream) {
    const float* q  = (const float*)d_in[0];
    const float* k  = (const float*)d_in[1];
    const float* v  = (const float*)d_in[2];
    const float* w1 = (const float*)d_in[3];
    const float* b1 = (const float*)d_in[4];
    const float* w2 = (const float*)d_in[5];
    const float* b2 = (const float*)d_in[6];
    float* out = (float*)d_out;

    char* ws = (char*)d_ws;
    const size_t phiBytes = (size_t)BH*SEQ*FF*sizeof(u16);   // 50,331,648
    u16* qphi   = (u16*)ws;
    u16* kphi   = (u16*)(ws + phiBytes);
    u16* chunkT = (u16*)(ws + 2*phiBytes);   // becomes prefT in-place after scan
    u16* sufT   = (u16*)(ws + 3*phiBytes);
    u16* w1t    = (u16*)(ws + 4*phiBytes);               // 256*136*2 = 69,632 B
    u16* w2t    = w1t + 256*136;                         // 256*264*2 = 135,168 B

    prep_kernel<<<dim3(100), 256, 0, stream>>>(w1, w2, w1t, w2t);
    phi_fused_kernel<<<dim3(2*(BH*SEQ)/PTOK), 512, 0, stream>>>(q, k, b1, b2, w1t, w2t, qphi, kphi);
    kvsum_kernel<<<dim3(NC, BH), 256, 0, stream>>>(kphi, v, chunkT);
    scan_kernel<<<dim3(384), 256, 0, stream>>>(chunkT, sufT);
    out_kernel<<<dim3(NC, BH), 512, 0, stream>>>(qphi, kphi, v, chunkT, sufT, out);
}

// Round 10
// 355.125 us; speedup vs baseline: 1.1553x; 1.0895x over previous
//
#include <hip/hip_runtime.h>

#define BH  24
#define SEQ 4096
#define DIM 128
#define FF  256
#define CHK 128
#define NC  32
#define SLOT (FF*DIM)

typedef unsigned short u16;
typedef unsigned int   u32;
typedef short  s16x8 __attribute__((ext_vector_type(8)));
typedef float  f32x4 __attribute__((ext_vector_type(4)));

#define MFMA16(a,b,c) __builtin_amdgcn_mfma_f32_16x16x32_bf16(a,b,c,0,0,0)

static __device__ __forceinline__ float bf2f(u16 u) {
    return __uint_as_float(((u32)u) << 16);
}
static __device__ __forceinline__ u16 f2bf(float f) {
    u32 u = __float_as_uint(f);
    u += 0x7fffu + ((u >> 16) & 1u);
    return (u16)(u >> 16);
}
// packed RNE f32x2 -> bf16x2 (lo in [15:0], hi in [31:16])
static __device__ __forceinline__ u32 cvtpk(float lo, float hi) {
    u32 r;
    asm("v_cvt_pk_bf16_f32 %0, %1, %2" : "=v"(r) : "v"(lo), "v"(hi));
    return r;
}

// ---------------- weight prep: FRAGMENT-MAJOR bf16 layouts -------------------
// w1f[((ft*4+kk)*64 + lane)*8 + e] = w1[d][f],  f = ft*16+(lane&15),
//     d = kk*32+(lane>>4)*8+e.   (16 ft x 4 kk x 64 lanes x 8) = 65,536 B
// w2f[((ft*8+kk)*64 + lane)*8 + e] = w2[fk][e], e-col = ft*16+(lane&15),
//     fk = kk*32+(lane>>4)*8+e.  (16 ft x 8 kk x 64 lanes x 8) = 131,072 B
// -> each B-fragment load in phi is base + lane*16B: ONE coalesced 1KB access.
__global__ __launch_bounds__(256) void prep_kernel(
    const float* __restrict__ w1, const float* __restrict__ w2,
    u16* __restrict__ w1f, u16* __restrict__ w2f)
{
    int idx = blockIdx.x * 256 + threadIdx.x;
    int stride = gridDim.x * 256;
    for (int i = idx; i < 16*4*64*8; i += stride) {
        int e = i & 7, lane = (i >> 3) & 63, kk = (i >> 9) & 3, ft = i >> 11;
        int f = ft*16 + (lane & 15);
        int d = kk*32 + (lane >> 4)*8 + e;
        w1f[i] = f2bf(w1[d*FF + f]);
    }
    for (int i = idx; i < 16*8*64*8; i += stride) {
        int e = i & 7, lane = (i >> 3) & 63, kk = (i >> 9) & 7, ft = i >> 12;
        int ec = ft*16 + (lane & 15);
        int fk = kk*32 + (lane >> 4)*8 + e;
        w2f[i] = f2bf(w2[fk*FF + ec]);
    }
}

// ---------------- fused phi via MFMA: y = silu(x@W1+b1)@W2 + b2 --------------
// R9 structure (128 us); weights now read via fragment-major coalesced loads.
#define PTOK 64
#define XS_OFF   0
#define HS_OFF   0
#define YB_OFF   0
#define ARENA_U16 16896   // 33,792 B

__global__ __launch_bounds__(512) void phi_fused_kernel(
    const float* __restrict__ xq, const float* __restrict__ xk,
    const float* __restrict__ b1, const float* __restrict__ b2,
    const u16* __restrict__ w1f, const u16* __restrict__ w2f,
    u16* __restrict__ yq, u16* __restrict__ yk)
{
    __shared__ __align__(16) u16 arena[ARENA_U16];
    const int tid = threadIdx.x;
    int b = blockIdx.x;
    const int nB = (BH*SEQ)/PTOK;   // 1536
    const float* xin; u16* yout;
    if (b < nB) { xin = xq; yout = yq; }
    else        { xin = xk; yout = yk; b -= nB; }
    const size_t tok0 = (size_t)b * PTOK;

    const int w = tid >> 6, lane = tid & 63;
    const int m = lane & 15, q = lane >> 4;
    const int wr = w >> 2, wc = w & 3;
    const f32x4 zero4 = {0.f, 0.f, 0.f, 0.f};

    // ---- stage XS (fp32 -> bf16 via cvt_pk), [64][136] ---------------------
    {
        const float4* xsrc = reinterpret_cast<const float4*>(xin + tok0*DIM);
        for (int i = tid; i < PTOK*DIM/4; i += 512) {
            int row = i >> 5, c4 = i & 31;
            float4 xv = xsrc[i];
            *reinterpret_cast<uint2*>(arena + XS_OFF + row*136 + c4*4) =
                make_uint2(cvtpk(xv.x, xv.y), cvtpk(xv.z, xv.w));
        }
    }
    __syncthreads();   // sync1: XS visible

    // ---- GEMM1: H[64][256] = XS @ W1 (B-frags coalesced from w1f), K=128 ---
    f32x4 acc[2][4];
    #pragma unroll
    for (int i = 0; i < 2; ++i)
        #pragma unroll
        for (int ct = 0; ct < 4; ++ct) acc[i][ct] = zero4;

    #pragma unroll
    for (int kk = 0; kk < 4; ++kk) {
        int ko = kk*32 + q*8;
        s16x8 a[2], bb[4];
        #pragma unroll
        for (int ct = 0; ct < 4; ++ct)
            bb[ct] = *reinterpret_cast<const s16x8*>(w1f + (size_t)(((wc*4 + ct)*4 + kk)*64 + lane)*8);
        #pragma unroll
        for (int i = 0; i < 2; ++i)
            a[i] = *reinterpret_cast<const s16x8*>(arena + XS_OFF + (wr*32 + i*16 + m)*136 + ko);
        #pragma unroll
        for (int i = 0; i < 2; ++i)
            #pragma unroll
            for (int ct = 0; ct < 4; ++ct)
                acc[i][ct] = MFMA16(a[i], bb[ct], acc[i][ct]);
    }
    __syncthreads();   // sync2: XS reads done; HS overwrites that space

    // ---- bias + SiLU (rcp approx), write HS bf16 [64][264] -----------------
    {
        float b1v[4];
        #pragma unroll
        for (int ct = 0; ct < 4; ++ct) b1v[ct] = b1[wc*64 + ct*16 + m];
        #pragma unroll
        for (int i = 0; i < 2; ++i) {
            #pragma unroll
            for (int ct = 0; ct < 4; ++ct) {
                #pragma unroll
                for (int reg = 0; reg < 4; ++reg) {
                    float h = acc[i][ct][reg] + b1v[ct];
                    h = h * __builtin_amdgcn_rcpf(1.0f + __expf(-h));
                    arena[HS_OFF + (size_t)(wr*32 + i*16 + q*4 + reg)*264 + (wc*64 + ct*16 + m)] = f2bf(h);
                }
            }
        }
    }
    __syncthreads();   // sync3: HS visible

    // ---- GEMM2: Y[64][256] = HS @ W2 (B-frags coalesced from w2f), K=256 ---
    f32x4 acc2[2][4];
    #pragma unroll
    for (int i = 0; i < 2; ++i)
        #pragma unroll
        for (int ct = 0; ct < 4; ++ct) acc2[i][ct] = zero4;

    #pragma unroll
    for (int kk = 0; kk < 8; ++kk) {
        int ko = kk*32 + q*8;
        s16x8 a[2], bb[4];
        #pragma unroll
        for (int ct = 0; ct < 4; ++ct)
            bb[ct] = *reinterpret_cast<const s16x8*>(w2f + (size_t)(((wc*4 + ct)*8 + kk)*64 + lane)*8);
        #pragma unroll
        for (int i = 0; i < 2; ++i)
            a[i] = *reinterpret_cast<const s16x8*>(arena + HS_OFF + (size_t)(wr*32 + i*16 + m)*264 + ko);
        #pragma unroll
        for (int i = 0; i < 2; ++i)
            #pragma unroll
            for (int ct = 0; ct < 4; ++ct)
                acc2[i][ct] = MFMA16(a[i], bb[ct], acc2[i][ct]);
    }
    __syncthreads();   // sync4: HS reads done; YB overwrites

    // ---- bias, Y -> LDS, coalesced uint4 store -----------------------------
    {
        float b2v[4];
        #pragma unroll
        for (int ct = 0; ct < 4; ++ct) b2v[ct] = b2[wc*64 + ct*16 + m];
        #pragma unroll
        for (int i = 0; i < 2; ++i) {
            #pragma unroll
            for (int ct = 0; ct < 4; ++ct) {
                #pragma unroll
                for (int reg = 0; reg < 4; ++reg) {
                    float y = acc2[i][ct][reg] + b2v[ct];
                    arena[YB_OFF + (size_t)(wr*32 + i*16 + q*4 + reg)*264 + (wc*64 + ct*16 + m)] = f2bf(y);
                }
            }
        }
    }
    __syncthreads();   // sync5: YB visible
    {
        uint4* dst = reinterpret_cast<uint4*>(yout + tok0*FF);
        const uint4* srcy = reinterpret_cast<const uint4*>(arena + YB_OFF);
        for (int i = tid; i < PTOK*32; i += 512) {
            int row = i >> 5, c = i & 31;
            dst[i] = srcy[row*33 + c];
        }
    }
}

// ------- per-(head,chunk) KV sums via MFMA -> bf16 TRANSPOSED [d][f] ---------
#define KVA_OFF 0
#define KVB_OFF (128*72)
#define KV_U16  (128*72 + 256*72)   // 55,296 B

__global__ __launch_bounds__(256) void kvsum_kernel(
    const u16* __restrict__ kphi, const float* __restrict__ v,
    u16* __restrict__ chunkT)
{
    __shared__ __align__(16) u16 kv[KV_U16];
    const int c = blockIdx.x, h = blockIdx.y, tid = threadIdx.x;
    const int w = tid >> 6, lane = tid & 63;
    const int m = lane & 15, q = lane >> 4;
    const int wr = w >> 1, wc = w & 1;
    const size_t tok0 = (size_t)h*SEQ + (size_t)c*CHK;
    const f32x4 zero4 = {0.f, 0.f, 0.f, 0.f};

    f32x4 acc[8][4];
    #pragma unroll
    for (int i = 0; i < 8; ++i)
        #pragma unroll
        for (int ct = 0; ct < 4; ++ct) acc[i][ct] = zero4;

    for (int tc = 0; tc < 2; ++tc) {
        {
            const u16* kb = kphi + (tok0 + tc*64)*FF + tid;
            #pragma unroll
            for (int tg = 0; tg < 8; ++tg) {
                u16 vals[8];
                #pragma unroll
                for (int tt = 0; tt < 8; ++tt)
                    vals[tt] = kb[(size_t)(tg*8 + tt)*FF];
                uint4 p;
                p.x = (u32)vals[0] | ((u32)vals[1] << 16);
                p.y = (u32)vals[2] | ((u32)vals[3] << 16);
                p.z = (u32)vals[4] | ((u32)vals[5] << 16);
                p.w = (u32)vals[6] | ((u32)vals[7] << 16);
                *reinterpret_cast<uint4*>(kv + KVB_OFF + tid*72 + tg*8) = p;
            }
        }
        {
            const int d  = tid & 127;
            const int th = tid >> 7;
            const float* vb = v + (tok0 + tc*64 + th*32)*DIM + d;
            #pragma unroll
            for (int tg = 0; tg < 4; ++tg) {
                float fv[8];
                #pragma unroll
                for (int tt = 0; tt < 8; ++tt)
                    fv[tt] = vb[(size_t)(tg*8 + tt)*DIM];
                uint4 p;
                p.x = cvtpk(fv[0], fv[1]);
                p.y = cvtpk(fv[2], fv[3]);
                p.z = cvtpk(fv[4], fv[5]);
                p.w = cvtpk(fv[6], fv[7]);
                *reinterpret_cast<uint4*>(kv + KVA_OFF + d*72 + th*32 + tg*8) = p;
            }
        }
        __syncthreads();

        #pragma unroll
        for (int k2 = 0; k2 < 2; ++k2) {
            const int ko = k2*32 + q*8;
            s16x8 a[8], bb[4];
            #pragma unroll
            for (int i = 0; i < 8; ++i)
                a[i] = *reinterpret_cast<const s16x8*>(kv + KVB_OFF + (wc*128 + i*16 + m)*72 + ko);
            #pragma unroll
            for (int ct = 0; ct < 4; ++ct)
                bb[ct] = *reinterpret_cast<const s16x8*>(kv + KVA_OFF + (wr*64 + ct*16 + m)*72 + ko);
            #pragma unroll
            for (int i = 0; i < 8; ++i)
                #pragma unroll
                for (int ct = 0; ct < 4; ++ct)
                    acc[i][ct] = MFMA16(a[i], bb[ct], acc[i][ct]);
        }
        __syncthreads();
    }

    u16* outp = chunkT + (size_t)(h*NC + c)*SLOT;
    #pragma unroll
    for (int i = 0; i < 8; ++i) {
        const int f0 = wc*128 + i*16 + q*4;
        #pragma unroll
        for (int ct = 0; ct < 4; ++ct) {
            const int d = wr*64 + ct*16 + m;
            *reinterpret_cast<uint2*>(outp + (size_t)d*FF + f0) =
                make_uint2(cvtpk(acc[i][ct][0], acc[i][ct][1]),
                           cvtpk(acc[i][ct][2], acc[i][ct][3]));
        }
    }
}

// ---------------- elementwise scan over chunks (layout-agnostic, proven) -----
__global__ __launch_bounds__(256) void scan_kernel(
    u16* __restrict__ chunkT, u16* __restrict__ sufT)
{
    const int g = blockIdx.x * 256 + threadIdx.x;
    const int h = g >> 12;
    const int e = (g & 4095) * 8;
    u16* base  = chunkT + (size_t)h*NC*SLOT + e;
    u16* sbase = sufT   + (size_t)h*NC*SLOT + e;

    float tot[8];
    #pragma unroll
    for (int i = 0; i < 8; ++i) tot[i] = 0.f;
    for (int c = 0; c < NC; ++c) {
        uint4 r = *reinterpret_cast<const uint4*>(base + (size_t)c*SLOT);
        tot[0] += __uint_as_float(r.x << 16);
        tot[1] += __uint_as_float(r.x & 0xffff0000u);
        tot[2] += __uint_as_float(r.y << 16);
        tot[3] += __uint_as_float(r.y & 0xffff0000u);
        tot[4] += __uint_as_float(r.z << 16);
        tot[5] += __uint_as_float(r.z & 0xffff0000u);
        tot[6] += __uint_as_float(r.w << 16);
        tot[7] += __uint_as_float(r.w & 0xffff0000u);
    }
    float run[8];
    #pragma unroll
    for (int i = 0; i < 8; ++i) run[i] = 0.f;
    for (int c = 0; c < NC; ++c) {
        uint4 r = *reinterpret_cast<const uint4*>(base + (size_t)c*SLOT);
        float old[8];
        old[0] = __uint_as_float(r.x << 16);
        old[1] = __uint_as_float(r.x & 0xffff0000u);
        old[2] = __uint_as_float(r.y << 16);
        old[3] = __uint_as_float(r.y & 0xffff0000u);
        old[4] = __uint_as_float(r.z << 16);
        old[5] = __uint_as_float(r.z & 0xffff0000u);
        old[6] = __uint_as_float(r.w << 16);
        old[7] = __uint_as_float(r.w & 0xffff0000u);
        uint4 wp, wsuf;
        wp.x = cvtpk(run[0], run[1]);
        wp.y = cvtpk(run[2], run[3]);
        wp.z = cvtpk(run[4], run[5]);
        wp.w = cvtpk(run[6], run[7]);
        *reinterpret_cast<uint4*>(base + (size_t)c*SLOT) = wp;
        #pragma unroll
        for (int i = 0; i < 8; ++i) run[i] += old[i];
        float sf[8];
        #pragma unroll
        for (int i = 0; i < 8; ++i) sf[i] = tot[i] - run[i];
        wsuf.x = cvtpk(sf[0], sf[1]);
        wsuf.y = cvtpk(sf[2], sf[3]);
        wsuf.z = cvtpk(sf[4], sf[5]);
        wsuf.w = cvtpk(sf[6], sf[7]);
        *reinterpret_cast<uint4*>(sbase + (size_t)c*SLOT) = wsuf;
    }
}

// ------- output: all-MFMA, LDS-staged B streams (read once, coalesced) ------
#define VT_OFF 0
#define SF_OFF (128*136)
#define WB_OFF (2*128*136)
#define OARENA_U16 (2*128*136 + 128*264)   // 68,608 u16 = 137,216 B

__global__ __launch_bounds__(512, 2) void out_kernel(
    const u16* __restrict__ qphi, const u16* __restrict__ kphi,
    const float* __restrict__ v,
    const u16* __restrict__ prefT, const u16* __restrict__ sufT,
    float* __restrict__ out)
{
    __shared__ __align__(16) u16 arena[OARENA_U16];
    const int c = blockIdx.x, h = blockIdx.y;
    const int tid = threadIdx.x;
    const int w = tid >> 6, lane = tid & 63;
    const int m = lane & 15, q = lane >> 4;
    const size_t tok0 = (size_t)h*SEQ + (size_t)c*CHK;
    const u16* qbase = qphi + tok0*FF;
    const int R = w*16;
    const int rowA = R + m;
    const f32x4 zero4 = {0.f, 0.f, 0.f, 0.f};

    // ---- stage VT (v^T bf16 [d][j], stride 136) ----------------------------
    {
        const int d  = tid & 127;
        const int j0 = (tid >> 7) * 8;
        const float* vb = v + tok0*DIM + d;
        #pragma unroll
        for (int jb = 0; jb < 4; ++jb) {
            const int jbase = jb*32 + j0;
            float vals[8];
            #pragma unroll
            for (int t = 0; t < 8; ++t) vals[t] = vb[(size_t)(jbase + t)*DIM];
            uint4 p;
            p.x = cvtpk(vals[0], vals[1]);
            p.y = cvtpk(vals[2], vals[3]);
            p.z = cvtpk(vals[4], vals[5]);
            p.w = cvtpk(vals[6], vals[7]);
            *reinterpret_cast<uint4*>(arena + VT_OFF + d*136 + jbase) = p;
        }
    }
    // ---- stage kphi -> WB (coalesced uint4, stride 264 = 33 uint4) ---------
    {
        const uint4* src = reinterpret_cast<const uint4*>(kphi + tok0*FF);
        uint4* dst = reinterpret_cast<uint4*>(arena + WB_OFF);
        for (int i = tid; i < 128*32; i += 512) {
            int row = i >> 5, cc = i & 31;
            dst[row*33 + cc] = src[i];
        }
    }
    __syncthreads();   // barrier1: VT + kphi visible

    s16x8 qreg[8];
    #pragma unroll
    for (int kk = 0; kk < 8; ++kk)
        qreg[kk] = *reinterpret_cast<const s16x8*>(qbase + (size_t)rowA*FF + kk*32 + q*8);

    // ---- phase 1: S = Qphi Kphi^T (B from WB LDS), write bf16 SF -----------
    {
        f32x4 sacc[8];
        #pragma unroll
        for (int ct = 0; ct < 8; ++ct) sacc[ct] = zero4;
        for (int kk = 0; kk < 8; ++kk) {
            const int ko = kk*32 + q*8;
            #pragma unroll
            for (int ct = 0; ct < 8; ++ct) {
                s16x8 b = *reinterpret_cast<const s16x8*>(arena + WB_OFF + (size_t)(ct*16 + m)*264 + ko);
                sacc[ct] = MFMA16(qreg[kk], b, sacc[ct]);
            }
        }
        #pragma unroll
        for (int ct = 0; ct < 8; ++ct) {
            #pragma unroll
            for (int reg = 0; reg < 4; ++reg)
                arena[SF_OFF + (size_t)(R + q*4 + reg)*136 + (ct*16 + m)] = f2bf(sacc[ct][reg]);
        }
    }
    __syncthreads();   // barrier2: SF visible, WB (kphi) reads done

    f32x4 accA[8], accB[8];
    #pragma unroll
    for (int ct = 0; ct < 8; ++ct) { accA[ct] = zero4; accB[ct] = zero4; }

    uint4 stg[8];
    {
        const uint4* src = reinterpret_cast<const uint4*>(prefT + (size_t)(h*NC + c)*SLOT);
        #pragma unroll
        for (int i = 0; i < 8; ++i) stg[i] = src[tid + i*512];
    }

    // ---- phase 2: intra via triangular-masked MFMA GEMMs (SF x VT) ---------
    #pragma unroll
    for (int kk = 0; kk < 4; ++kk) {
        const int ko = kk*32 + q*8;
        s16x8 b[8];
        #pragma unroll
        for (int ct = 0; ct < 8; ++ct)
            b[ct] = *reinterpret_cast<const s16x8*>(arena + VT_OFF + (size_t)(ct*16 + m)*136 + ko);
        const bool anyLow  = (kk*32       <= R + 15);
        const bool lowFull = (kk*32 + 31  <= R);
        const bool anyUp   = (kk*32 + 31  >= R);
        const bool upFull  = (kk*32       >= R + 16);
        s16x8 a = *reinterpret_cast<const s16x8*>(arena + SF_OFF + (size_t)rowA*136 + ko);
        if (anyLow) {
            s16x8 aL;
            if (lowFull) aL = a;
            else {
                #pragma unroll
                for (int e = 0; e < 8; ++e)
                    aL[e] = (kk*32 + q*8 + e <= rowA) ? a[e] : (short)0;
            }
            #pragma unroll
            for (int ct = 0; ct < 8; ++ct)
                accA[ct] = MFMA16(aL, b[ct], accA[ct]);
        }
        if (anyUp) {
            s16x8 aU;
            if (upFull) aU = a;
            else {
                #pragma unroll
                for (int e = 0; e < 8; ++e)
                    aU[e] = (kk*32 + q*8 + e >= rowA) ? a[e] : (short)0;
            }
            #pragma unroll
            for (int ct = 0; ct < 8; ++ct)
                accB[ct] = MFMA16(aU, b[ct], accB[ct]);
        }
    }

    {
        uint4* dst = reinterpret_cast<uint4*>(arena + WB_OFF);
        #pragma unroll
        for (int i = 0; i < 8; ++i) {
            int idx = tid + i*512;
            int row = idx >> 5, cc = idx & 31;
            dst[row*33 + cc] = stg[i];
        }
    }
    __syncthreads();   // barrier3: pref visible, VT/SF reads done

    {
        const uint4* src = reinterpret_cast<const uint4*>(sufT + (size_t)(h*NC + c)*SLOT);
        #pragma unroll
        for (int i = 0; i < 8; ++i) stg[i] = src[tid + i*512];
    }

    // ---- phase 3a: accA += Q . pref (B from WB) ----------------------------
    for (int kk = 0; kk < 8; ++kk) {
        const int ko = kk*32 + q*8;
        #pragma unroll
        for (int nt = 0; nt < 8; ++nt) {
            s16x8 bp = *reinterpret_cast<const s16x8*>(arena + WB_OFF + (size_t)(nt*16 + m)*264 + ko);
            accA[nt] = MFMA16(qreg[kk], bp, accA[nt]);
        }
    }

    {
        uint4* dst = reinterpret_cast<uint4*>(arena);
        #pragma unroll
        for (int i = 0; i < 8; ++i) {
            int idx = tid + i*512;
            int row = idx >> 5, cc = idx & 31;
            dst[row*33 + cc] = stg[i];
        }
    }
    __syncthreads();   // barrier4: suf visible, WB (pref) reads done

    // ---- phase 3b: accB += Q . suf -----------------------------------------
    for (int kk = 0; kk < 8; ++kk) {
        const int ko = kk*32 + q*8;
        #pragma unroll
        for (int nt = 0; nt < 8; ++nt) {
            s16x8 bs = *reinterpret_cast<const s16x8*>(arena + (size_t)(nt*16 + m)*264 + ko);
            accB[nt] = MFMA16(qreg[kk], bs, accB[nt]);
        }
    }

    // ---- epilogue ----------------------------------------------------------
    #pragma unroll
    for (int reg = 0; reg < 4; ++reg) {
        const int row = R + q*4 + reg;
        const int pos = c*CHK + row;
        const float ia = 1.0f / (float)(pos + 1);
        const float ib = 1.0f / (float)(SEQ - pos);
        float* orow = out + (tok0 + (size_t)row)*DIM;
        #pragma unroll
        for (int ct = 0; ct < 8; ++ct)
            orow[ct*16 + m] = accA[ct][reg]*ia + accB[ct][reg]*ib;
    }
}

extern "C" void kernel_launch(void* const* d_in, const int* in_sizes, int n_in,
                              void* d_out, int out_size, void* d_ws, size_t ws_size,
                              hipStream_t stream) {
    const float* q  = (const float*)d_in[0];
    const float* k  = (const float*)d_in[1];
    const float* v  = (const float*)d_in[2];
    const float* w1 = (const float*)d_in[3];
    const float* b1 = (const float*)d_in[4];
    const float* w2 = (const float*)d_in[5];
    const float* b2 = (const float*)d_in[6];
    float* out = (float*)d_out;

    char* ws = (char*)d_ws;
    const size_t phiBytes = (size_t)BH*SEQ*FF*sizeof(u16);   // 50,331,648
    u16* qphi   = (u16*)ws;
    u16* kphi   = (u16*)(ws + phiBytes);
    u16* chunkT = (u16*)(ws + 2*phiBytes);   // becomes prefT in-place after scan
    u16* sufT   = (u16*)(ws + 3*phiBytes);
    u16* w1f    = (u16*)(ws + 4*phiBytes);               // 65,536 B
    u16* w2f    = w1f + 16*4*64*8;                       // 131,072 B

    prep_kernel<<<dim3(100), 256, 0, stream>>>(w1, w2, w1f, w2f);
    phi_fused_kernel<<<dim3(2*(BH*SEQ)/PTOK), 512, 0, stream>>>(q, k, b1, b2, w1f, w2f, qphi, kphi);
    kvsum_kernel<<<dim3(NC, BH), 256, 0, stream>>>(kphi, v, chunkT);
    scan_kernel<<<dim3(384), 256, 0, stream>>>(chunkT, sufT);
    out_kernel<<<dim3(NC, BH), 512, 0, stream>>>(qphi, kphi, v, chunkT, sufT, out);
}

// Round 11
// 351.873 us; speedup vs baseline: 1.1660x; 1.0092x over previous
//
#include <hip/hip_runtime.h>

#define BH  24
#define SEQ 4096
#define DIM 128
#define FF  256
#define CHK 128
#define NC  32
#define SLOT (FF*DIM)

typedef unsigned short u16;
typedef unsigned int   u32;
typedef short  s16x8 __attribute__((ext_vector_type(8)));
typedef float  f32x4 __attribute__((ext_vector_type(4)));

#define MFMA16(a,b,c) __builtin_amdgcn_mfma_f32_16x16x32_bf16(a,b,c,0,0,0)

static __device__ __forceinline__ float bf2f(u16 u) {
    return __uint_as_float(((u32)u) << 16);
}
static __device__ __forceinline__ u16 f2bf(float f) {
    u32 u = __float_as_uint(f);
    u += 0x7fffu + ((u >> 16) & 1u);
    return (u16)(u >> 16);
}
// packed RNE f32x2 -> bf16x2 (lo in [15:0], hi in [31:16])
static __device__ __forceinline__ u32 cvtpk(float lo, float hi) {
    u32 r;
    asm("v_cvt_pk_bf16_f32 %0, %1, %2" : "=v"(r) : "v"(lo), "v"(hi));
    return r;
}

// ---------------- weight prep: FRAGMENT-MAJOR bf16 layouts -------------------
// w1f[((ft*4+kk)*64 + lane)*8 + e] = w1[d][f],  f = ft*16+(lane&15),
//     d = kk*32+(lane>>4)*8+e.
// w2f[((ft*8+kk)*64 + lane)*8 + e] = w2[fk][e], e-col = ft*16+(lane&15),
//     fk = kk*32+(lane>>4)*8+e.
// Fragment loads are base + lane*16B: ONE coalesced 1KB access. Works as
// either MFMA operand (A and B share the per-lane row/k layout).
__global__ __launch_bounds__(256) void prep_kernel(
    const float* __restrict__ w1, const float* __restrict__ w2,
    u16* __restrict__ w1f, u16* __restrict__ w2f)
{
    int idx = blockIdx.x * 256 + threadIdx.x;
    int stride = gridDim.x * 256;
    for (int i = idx; i < 16*4*64*8; i += stride) {
        int e = i & 7, lane = (i >> 3) & 63, kk = (i >> 9) & 3, ft = i >> 11;
        int f = ft*16 + (lane & 15);
        int d = kk*32 + (lane >> 4)*8 + e;
        w1f[i] = f2bf(w1[d*FF + f]);
    }
    for (int i = idx; i < 16*8*64*8; i += stride) {
        int e = i & 7, lane = (i >> 3) & 63, kk = (i >> 9) & 7, ft = i >> 12;
        int ec = ft*16 + (lane & 15);
        int fk = kk*32 + (lane >> 4)*8 + e;
        w2f[i] = f2bf(w2[fk*FF + ec]);
    }
}

// ---------------- fused phi via MFMA: y = silu(x@W1+b1)@W2 + b2 --------------
// R10 structure + FLIPPED GEMM orientation: A = weight fragment, B = token
// rows -> C[f][token] / C[e][token]; lane's 4 C-regs contiguous in f/e ->
// cvt_pk packed b64 LDS writes (kills scalar f2bf epilogues). Y store stays
// STAGED + coalesced (R8's direct-scatter mistake avoided).
#define PTOK 64
#define XS_OFF   0
#define HS_OFF   0
#define YB_OFF   0
#define ARENA_U16 16896   // 33,792 B

__global__ __launch_bounds__(512) void phi_fused_kernel(
    const float* __restrict__ xq, const float* __restrict__ xk,
    const float* __restrict__ b1, const float* __restrict__ b2,
    const u16* __restrict__ w1f, const u16* __restrict__ w2f,
    u16* __restrict__ yq, u16* __restrict__ yk)
{
    __shared__ __align__(16) u16 arena[ARENA_U16];
    const int tid = threadIdx.x;
    int b = blockIdx.x;
    const int nB = (BH*SEQ)/PTOK;   // 1536
    const float* xin; u16* yout;
    if (b < nB) { xin = xq; yout = yq; }
    else        { xin = xk; yout = yk; b -= nB; }
    const size_t tok0 = (size_t)b * PTOK;

    const int w = tid >> 6, lane = tid & 63;
    const int m = lane & 15, q = lane >> 4;
    const int wr = w >> 2, wc = w & 3;   // wr: token group(32), wc: f/e group(64)
    const f32x4 zero4 = {0.f, 0.f, 0.f, 0.f};

    // ---- stage XS (fp32 -> bf16 via cvt_pk), [64][136] ---------------------
    {
        const float4* xsrc = reinterpret_cast<const float4*>(xin + tok0*DIM);
        for (int i = tid; i < PTOK*DIM/4; i += 512) {
            int row = i >> 5, c4 = i & 31;
            float4 xv = xsrc[i];
            *reinterpret_cast<uint2*>(arena + XS_OFF + row*136 + c4*4) =
                make_uint2(cvtpk(xv.x, xv.y), cvtpk(xv.z, xv.w));
        }
    }
    __syncthreads();   // sync1: XS visible

    // ---- GEMM1 (flipped): C[f][token]; A = w1f frag, B = XS token rows -----
    f32x4 acc[4][2];   // [f-tile ct][token-tile i]
    #pragma unroll
    for (int ct = 0; ct < 4; ++ct)
        #pragma unroll
        for (int i = 0; i < 2; ++i) acc[ct][i] = zero4;

    #pragma unroll
    for (int kk = 0; kk < 4; ++kk) {
        int ko = kk*32 + q*8;
        s16x8 wfrag[4], xfrag[2];
        #pragma unroll
        for (int ct = 0; ct < 4; ++ct)
            wfrag[ct] = *reinterpret_cast<const s16x8*>(w1f + (size_t)(((wc*4 + ct)*4 + kk)*64 + lane)*8);
        #pragma unroll
        for (int i = 0; i < 2; ++i)
            xfrag[i] = *reinterpret_cast<const s16x8*>(arena + XS_OFF + (wr*32 + i*16 + m)*136 + ko);
        #pragma unroll
        for (int ct = 0; ct < 4; ++ct)
            #pragma unroll
            for (int i = 0; i < 2; ++i)
                acc[ct][i] = MFMA16(wfrag[ct], xfrag[i], acc[ct][i]);
    }
    __syncthreads();   // sync2: XS reads done; HS overwrites that space

    // ---- bias + SiLU (rcp), packed b64 HS writes: HS[token][f] -------------
    #pragma unroll
    for (int ct = 0; ct < 4; ++ct) {
        const int f0 = wc*64 + ct*16 + q*4;
        const float4 b1v = *reinterpret_cast<const float4*>(b1 + f0);
        #pragma unroll
        for (int i = 0; i < 2; ++i) {
            const int token = wr*32 + i*16 + m;
            float h0 = acc[ct][i][0] + b1v.x;
            float h1 = acc[ct][i][1] + b1v.y;
            float h2 = acc[ct][i][2] + b1v.z;
            float h3 = acc[ct][i][3] + b1v.w;
            h0 = h0 * __builtin_amdgcn_rcpf(1.0f + __expf(-h0));
            h1 = h1 * __builtin_amdgcn_rcpf(1.0f + __expf(-h1));
            h2 = h2 * __builtin_amdgcn_rcpf(1.0f + __expf(-h2));
            h3 = h3 * __builtin_amdgcn_rcpf(1.0f + __expf(-h3));
            *reinterpret_cast<uint2*>(arena + HS_OFF + (size_t)token*264 + f0) =
                make_uint2(cvtpk(h0, h1), cvtpk(h2, h3));
        }
    }
    __syncthreads();   // sync3: HS visible

    // ---- GEMM2 (flipped): C[e][token]; A = w2f frag, B = HS token rows -----
    f32x4 acc2[4][2];
    #pragma unroll
    for (int ct = 0; ct < 4; ++ct)
        #pragma unroll
        for (int i = 0; i < 2; ++i) acc2[ct][i] = zero4;

    #pragma unroll
    for (int kk = 0; kk < 8; ++kk) {
        int ko = kk*32 + q*8;
        s16x8 wfrag[4], hfrag[2];
        #pragma unroll
        for (int ct = 0; ct < 4; ++ct)
            wfrag[ct] = *reinterpret_cast<const s16x8*>(w2f + (size_t)(((wc*4 + ct)*8 + kk)*64 + lane)*8);
        #pragma unroll
        for (int i = 0; i < 2; ++i)
            hfrag[i] = *reinterpret_cast<const s16x8*>(arena + HS_OFF + (size_t)(wr*32 + i*16 + m)*264 + ko);
        #pragma unroll
        for (int ct = 0; ct < 4; ++ct)
            #pragma unroll
            for (int i = 0; i < 2; ++i)
                acc2[ct][i] = MFMA16(wfrag[ct], hfrag[i], acc2[ct][i]);
    }
    __syncthreads();   // sync4: HS reads done; YB overwrites

    // ---- bias, packed b64 YB writes, then coalesced uint4 global store -----
    #pragma unroll
    for (int ct = 0; ct < 4; ++ct) {
        const int e0 = wc*64 + ct*16 + q*4;
        const float4 b2v = *reinterpret_cast<const float4*>(b2 + e0);
        #pragma unroll
        for (int i = 0; i < 2; ++i) {
            const int token = wr*32 + i*16 + m;
            float y0 = acc2[ct][i][0] + b2v.x;
            float y1 = acc2[ct][i][1] + b2v.y;
            float y2 = acc2[ct][i][2] + b2v.z;
            float y3 = acc2[ct][i][3] + b2v.w;
            *reinterpret_cast<uint2*>(arena + YB_OFF + (size_t)token*264 + e0) =
                make_uint2(cvtpk(y0, y1), cvtpk(y2, y3));
        }
    }
    __syncthreads();   // sync5: YB visible
    {
        uint4* dst = reinterpret_cast<uint4*>(yout + tok0*FF);
        const uint4* srcy = reinterpret_cast<const uint4*>(arena + YB_OFF);
        for (int i = tid; i < PTOK*32; i += 512) {
            int row = i >> 5, c = i & 31;
            dst[i] = srcy[row*33 + c];
        }
    }
}

// ------- per-(head,chunk) KV sums via MFMA -> bf16 TRANSPOSED [d][f] ---------
#define KVA_OFF 0
#define KVB_OFF (128*72)
#define KV_U16  (128*72 + 256*72)   // 55,296 B

__global__ __launch_bounds__(256) void kvsum_kernel(
    const u16* __restrict__ kphi, const float* __restrict__ v,
    u16* __restrict__ chunkT)
{
    __shared__ __align__(16) u16 kv[KV_U16];
    const int c = blockIdx.x, h = blockIdx.y, tid = threadIdx.x;
    const int w = tid >> 6, lane = tid & 63;
    const int m = lane & 15, q = lane >> 4;
    const int wr = w >> 1, wc = w & 1;
    const size_t tok0 = (size_t)h*SEQ + (size_t)c*CHK;
    const f32x4 zero4 = {0.f, 0.f, 0.f, 0.f};

    f32x4 acc[8][4];
    #pragma unroll
    for (int i = 0; i < 8; ++i)
        #pragma unroll
        for (int ct = 0; ct < 4; ++ct) acc[i][ct] = zero4;

    for (int tc = 0; tc < 2; ++tc) {
        {
            const u16* kb = kphi + (tok0 + tc*64)*FF + tid;
            #pragma unroll
            for (int tg = 0; tg < 8; ++tg) {
                u16 vals[8];
                #pragma unroll
                for (int tt = 0; tt < 8; ++tt)
                    vals[tt] = kb[(size_t)(tg*8 + tt)*FF];
                uint4 p;
                p.x = (u32)vals[0] | ((u32)vals[1] << 16);
                p.y = (u32)vals[2] | ((u32)vals[3] << 16);
                p.z = (u32)vals[4] | ((u32)vals[5] << 16);
                p.w = (u32)vals[6] | ((u32)vals[7] << 16);
                *reinterpret_cast<uint4*>(kv + KVB_OFF + tid*72 + tg*8) = p;
            }
        }
        {
            const int d  = tid & 127;
            const int th = tid >> 7;
            const float* vb = v + (tok0 + tc*64 + th*32)*DIM + d;
            #pragma unroll
            for (int tg = 0; tg < 4; ++tg) {
                float fv[8];
                #pragma unroll
                for (int tt = 0; tt < 8; ++tt)
                    fv[tt] = vb[(size_t)(tg*8 + tt)*DIM];
                uint4 p;
                p.x = cvtpk(fv[0], fv[1]);
                p.y = cvtpk(fv[2], fv[3]);
                p.z = cvtpk(fv[4], fv[5]);
                p.w = cvtpk(fv[6], fv[7]);
                *reinterpret_cast<uint4*>(kv + KVA_OFF + d*72 + th*32 + tg*8) = p;
            }
        }
        __syncthreads();

        #pragma unroll
        for (int k2 = 0; k2 < 2; ++k2) {
            const int ko = k2*32 + q*8;
            s16x8 a[8], bb[4];
            #pragma unroll
            for (int i = 0; i < 8; ++i)
                a[i] = *reinterpret_cast<const s16x8*>(kv + KVB_OFF + (wc*128 + i*16 + m)*72 + ko);
            #pragma unroll
            for (int ct = 0; ct < 4; ++ct)
                bb[ct] = *reinterpret_cast<const s16x8*>(kv + KVA_OFF + (wr*64 + ct*16 + m)*72 + ko);
            #pragma unroll
            for (int i = 0; i < 8; ++i)
                #pragma unroll
                for (int ct = 0; ct < 4; ++ct)
                    acc[i][ct] = MFMA16(a[i], bb[ct], acc[i][ct]);
        }
        __syncthreads();
    }

    u16* outp = chunkT + (size_t)(h*NC + c)*SLOT;
    #pragma unroll
    for (int i = 0; i < 8; ++i) {
        const int f0 = wc*128 + i*16 + q*4;
        #pragma unroll
        for (int ct = 0; ct < 4; ++ct) {
            const int d = wr*64 + ct*16 + m;
            *reinterpret_cast<uint2*>(outp + (size_t)d*FF + f0) =
                make_uint2(cvtpk(acc[i][ct][0], acc[i][ct][1]),
                           cvtpk(acc[i][ct][2], acc[i][ct][3]));
        }
    }
}

// ---------------- elementwise scan over chunks (layout-agnostic, proven) -----
__global__ __launch_bounds__(256) void scan_kernel(
    u16* __restrict__ chunkT, u16* __restrict__ sufT)
{
    const int g = blockIdx.x * 256 + threadIdx.x;
    const int h = g >> 12;
    const int e = (g & 4095) * 8;
    u16* base  = chunkT + (size_t)h*NC*SLOT + e;
    u16* sbase = sufT   + (size_t)h*NC*SLOT + e;

    float tot[8];
    #pragma unroll
    for (int i = 0; i < 8; ++i) tot[i] = 0.f;
    for (int c = 0; c < NC; ++c) {
        uint4 r = *reinterpret_cast<const uint4*>(base + (size_t)c*SLOT);
        tot[0] += __uint_as_float(r.x << 16);
        tot[1] += __uint_as_float(r.x & 0xffff0000u);
        tot[2] += __uint_as_float(r.y << 16);
        tot[3] += __uint_as_float(r.y & 0xffff0000u);
        tot[4] += __uint_as_float(r.z << 16);
        tot[5] += __uint_as_float(r.z & 0xffff0000u);
        tot[6] += __uint_as_float(r.w << 16);
        tot[7] += __uint_as_float(r.w & 0xffff0000u);
    }
    float run[8];
    #pragma unroll
    for (int i = 0; i < 8; ++i) run[i] = 0.f;
    for (int c = 0; c < NC; ++c) {
        uint4 r = *reinterpret_cast<const uint4*>(base + (size_t)c*SLOT);
        float old[8];
        old[0] = __uint_as_float(r.x << 16);
        old[1] = __uint_as_float(r.x & 0xffff0000u);
        old[2] = __uint_as_float(r.y << 16);
        old[3] = __uint_as_float(r.y & 0xffff0000u);
        old[4] = __uint_as_float(r.z << 16);
        old[5] = __uint_as_float(r.z & 0xffff0000u);
        old[6] = __uint_as_float(r.w << 16);
        old[7] = __uint_as_float(r.w & 0xffff0000u);
        uint4 wp, wsuf;
        wp.x = cvtpk(run[0], run[1]);
        wp.y = cvtpk(run[2], run[3]);
        wp.z = cvtpk(run[4], run[5]);
        wp.w = cvtpk(run[6], run[7]);
        *reinterpret_cast<uint4*>(base + (size_t)c*SLOT) = wp;
        #pragma unroll
        for (int i = 0; i < 8; ++i) run[i] += old[i];
        float sf[8];
        #pragma unroll
        for (int i = 0; i < 8; ++i) sf[i] = tot[i] - run[i];
        wsuf.x = cvtpk(sf[0], sf[1]);
        wsuf.y = cvtpk(sf[2], sf[3]);
        wsuf.z = cvtpk(sf[4], sf[5]);
        wsuf.w = cvtpk(sf[6], sf[7]);
        *reinterpret_cast<uint4*>(sbase + (size_t)c*SLOT) = wsuf;
    }
}

// ------- output: all-MFMA, LDS-staged B streams (read once, coalesced) ------
#define VT_OFF 0
#define SF_OFF (128*136)
#define WB_OFF (2*128*136)
#define OARENA_U16 (2*128*136 + 128*264)   // 68,608 u16 = 137,216 B

__global__ __launch_bounds__(512, 2) void out_kernel(
    const u16* __restrict__ qphi, const u16* __restrict__ kphi,
    const float* __restrict__ v,
    const u16* __restrict__ prefT, const u16* __restrict__ sufT,
    float* __restrict__ out)
{
    __shared__ __align__(16) u16 arena[OARENA_U16];
    const int c = blockIdx.x, h = blockIdx.y;
    const int tid = threadIdx.x;
    const int w = tid >> 6, lane = tid & 63;
    const int m = lane & 15, q = lane >> 4;
    const size_t tok0 = (size_t)h*SEQ + (size_t)c*CHK;
    const u16* qbase = qphi + tok0*FF;
    const int R = w*16;
    const int rowA = R + m;
    const f32x4 zero4 = {0.f, 0.f, 0.f, 0.f};

    // ---- stage VT (v^T bf16 [d][j], stride 136) ----------------------------
    {
        const int d  = tid & 127;
        const int j0 = (tid >> 7) * 8;
        const float* vb = v + tok0*DIM + d;
        #pragma unroll
        for (int jb = 0; jb < 4; ++jb) {
            const int jbase = jb*32 + j0;
            float vals[8];
            #pragma unroll
            for (int t = 0; t < 8; ++t) vals[t] = vb[(size_t)(jbase + t)*DIM];
            uint4 p;
            p.x = cvtpk(vals[0], vals[1]);
            p.y = cvtpk(vals[2], vals[3]);
            p.z = cvtpk(vals[4], vals[5]);
            p.w = cvtpk(vals[6], vals[7]);
            *reinterpret_cast<uint4*>(arena + VT_OFF + d*136 + jbase) = p;
        }
    }
    // ---- stage kphi -> WB (coalesced uint4, stride 264 = 33 uint4) ---------
    {
        const uint4* src = reinterpret_cast<const uint4*>(kphi + tok0*FF);
        uint4* dst = reinterpret_cast<uint4*>(arena + WB_OFF);
        for (int i = tid; i < 128*32; i += 512) {
            int row = i >> 5, cc = i & 31;
            dst[row*33 + cc] = src[i];
        }
    }
    __syncthreads();   // barrier1: VT + kphi visible

    s16x8 qreg[8];
    #pragma unroll
    for (int kk = 0; kk < 8; ++kk)
        qreg[kk] = *reinterpret_cast<const s16x8*>(qbase + (size_t)rowA*FF + kk*32 + q*8);

    // ---- phase 1: S = Qphi Kphi^T (B from WB LDS), write bf16 SF -----------
    {
        f32x4 sacc[8];
        #pragma unroll
        for (int ct = 0; ct < 8; ++ct) sacc[ct] = zero4;
        for (int kk = 0; kk < 8; ++kk) {
            const int ko = kk*32 + q*8;
            #pragma unroll
            for (int ct = 0; ct < 8; ++ct) {
                s16x8 b = *reinterpret_cast<const s16x8*>(arena + WB_OFF + (size_t)(ct*16 + m)*264 + ko);
                sacc[ct] = MFMA16(qreg[kk], b, sacc[ct]);
            }
        }
        #pragma unroll
        for (int ct = 0; ct < 8; ++ct) {
            #pragma unroll
            for (int reg = 0; reg < 4; ++reg)
                arena[SF_OFF + (size_t)(R + q*4 + reg)*136 + (ct*16 + m)] = f2bf(sacc[ct][reg]);
        }
    }
    __syncthreads();   // barrier2: SF visible, WB (kphi) reads done

    f32x4 accA[8], accB[8];
    #pragma unroll
    for (int ct = 0; ct < 8; ++ct) { accA[ct] = zero4; accB[ct] = zero4; }

    uint4 stg[8];
    {
        const uint4* src = reinterpret_cast<const uint4*>(prefT + (size_t)(h*NC + c)*SLOT);
        #pragma unroll
        for (int i = 0; i < 8; ++i) stg[i] = src[tid + i*512];
    }

    // ---- phase 2: intra via triangular-masked MFMA GEMMs (SF x VT) ---------
    #pragma unroll
    for (int kk = 0; kk < 4; ++kk) {
        const int ko = kk*32 + q*8;
        s16x8 b[8];
        #pragma unroll
        for (int ct = 0; ct < 8; ++ct)
            b[ct] = *reinterpret_cast<const s16x8*>(arena + VT_OFF + (size_t)(ct*16 + m)*136 + ko);
        const bool anyLow  = (kk*32       <= R + 15);
        const bool lowFull = (kk*32 + 31  <= R);
        const bool anyUp   = (kk*32 + 31  >= R);
        const bool upFull  = (kk*32       >= R + 16);
        s16x8 a = *reinterpret_cast<const s16x8*>(arena + SF_OFF + (size_t)rowA*136 + ko);
        if (anyLow) {
            s16x8 aL;
            if (lowFull) aL = a;
            else {
                #pragma unroll
                for (int e = 0; e < 8; ++e)
                    aL[e] = (kk*32 + q*8 + e <= rowA) ? a[e] : (short)0;
            }
            #pragma unroll
            for (int ct = 0; ct < 8; ++ct)
                accA[ct] = MFMA16(aL, b[ct], accA[ct]);
        }
        if (anyUp) {
            s16x8 aU;
            if (upFull) aU = a;
            else {
                #pragma unroll
                for (int e = 0; e < 8; ++e)
                    aU[e] = (kk*32 + q*8 + e >= rowA) ? a[e] : (short)0;
            }
            #pragma unroll
            for (int ct = 0; ct < 8; ++ct)
                accB[ct] = MFMA16(aU, b[ct], accB[ct]);
        }
    }

    {
        uint4* dst = reinterpret_cast<uint4*>(arena + WB_OFF);
        #pragma unroll
        for (int i = 0; i < 8; ++i) {
            int idx = tid + i*512;
            int row = idx >> 5, cc = idx & 31;
            dst[row*33 + cc] = stg[i];
        }
    }
    __syncthreads();   // barrier3: pref visible, VT/SF reads done

    {
        const uint4* src = reinterpret_cast<const uint4*>(sufT + (size_t)(h*NC + c)*SLOT);
        #pragma unroll
        for (int i = 0; i < 8; ++i) stg[i] = src[tid + i*512];
    }

    // ---- phase 3a: accA += Q . pref (B from WB) ----------------------------
    for (int kk = 0; kk < 8; ++kk) {
        const int ko = kk*32 + q*8;
        #pragma unroll
        for (int nt = 0; nt < 8; ++nt) {
            s16x8 bp = *reinterpret_cast<const s16x8*>(arena + WB_OFF + (size_t)(nt*16 + m)*264 + ko);
            accA[nt] = MFMA16(qreg[kk], bp, accA[nt]);
        }
    }

    {
        uint4* dst = reinterpret_cast<uint4*>(arena);
        #pragma unroll
        for (int i = 0; i < 8; ++i) {
            int idx = tid + i*512;
            int row = idx >> 5, cc = idx & 31;
            dst[row*33 + cc] = stg[i];
        }
    }
    __syncthreads();   // barrier4: suf visible, WB (pref) reads done

    // ---- phase 3b: accB += Q . suf -----------------------------------------
    for (int kk = 0; kk < 8; ++kk) {
        const int ko = kk*32 + q*8;
        #pragma unroll
        for (int nt = 0; nt < 8; ++nt) {
            s16x8 bs = *reinterpret_cast<const s16x8*>(arena + (size_t)(nt*16 + m)*264 + ko);
            accB[nt] = MFMA16(qreg[kk], bs, accB[nt]);
        }
    }

    // ---- epilogue ----------------------------------------------------------
    #pragma unroll
    for (int reg = 0; reg < 4; ++reg) {
        const int row = R + q*4 + reg;
        const int pos = c*CHK + row;
        const float ia = 1.0f / (float)(pos + 1);
        const float ib = 1.0f / (float)(SEQ - pos);
        float* orow = out + (tok0 + (size_t)row)*DIM;
        #pragma unroll
        for (int ct = 0; ct < 8; ++ct)
            orow[ct*16 + m] = accA[ct][reg]*ia + accB[ct][reg]*ib;
    }
}

extern "C" void kernel_launch(void* const* d_in, const int* in_sizes, int n_in,
                              void* d_out, int out_size, void* d_ws, size_t ws_size,
                              hipStream_t stream) {
    const float* q  = (const float*)d_in[0];
    const float* k  = (const float*)d_in[1];
    const float* v  = (const float*)d_in[2];
    const float* w1 = (const float*)d_in[3];
    const float* b1 = (const float*)d_in[4];
    const float* w2 = (const float*)d_in[5];
    const float* b2 = (const float*)d_in[6];
    float* out = (float*)d_out;

    char* ws = (char*)d_ws;
    const size_t phiBytes = (size_t)BH*SEQ*FF*sizeof(u16);   // 50,331,648
    u16* qphi   = (u16*)ws;
    u16* kphi   = (u16*)(ws + phiBytes);
    u16* chunkT = (u16*)(ws + 2*phiBytes);   // becomes prefT in-place after scan
    u16* sufT   = (u16*)(ws + 3*phiBytes);
    u16* w1f    = (u16*)(ws + 4*phiBytes);               // 65,536 B
    u16* w2f    = w1f + 16*4*64*8;                       // 131,072 B

    prep_kernel<<<dim3(100), 256, 0, stream>>>(w1, w2, w1f, w2f);
    phi_fused_kernel<<<dim3(2*(BH*SEQ)/PTOK), 512, 0, stream>>>(q, k, b1, b2, w1f, w2f, qphi, kphi);
    kvsum_kernel<<<dim3(NC, BH), 256, 0, stream>>>(kphi, v, chunkT);
    scan_kernel<<<dim3(384), 256, 0, stream>>>(chunkT, sufT);
    out_kernel<<<dim3(NC, BH), 512, 0, stream>>>(qphi, kphi, v, chunkT, sufT, out);
}